// Round 1
// baseline (564.894 us; speedup 1.0000x reference)
//
#include <hip/hip_runtime.h>
#include <hip/hip_bf16.h>
#include <math.h>

#define S_LEN 2048
#define D_MODEL 1024
#define N_BATCH 4
#define N_HALF 512

typedef unsigned short u16;
typedef __attribute__((ext_vector_type(8))) short bf16x8;
typedef __attribute__((ext_vector_type(4))) float f32x4;

// ---------- helpers ----------
__device__ inline u16 f2bf(float v) {
  __hip_bfloat16 h = __float2bfloat16(v);   // RNE
  return *reinterpret_cast<u16*>(&h);
}
__device__ inline float bf2f(u16 u) {
  __hip_bfloat16 h = *reinterpret_cast<__hip_bfloat16*>(&u);
  return __bfloat162float(h);
}
// async global->LDS, 16B per lane; LDS dest is wave-uniform base + lane*16
__device__ inline void gl2lds16(const void* g, void* l) {
  __builtin_amdgcn_global_load_lds(
      (const __attribute__((address_space(1))) unsigned int*)g,
      (__attribute__((address_space(3))) unsigned int*)l, 16, 0, 0);
}
// tanh via v_exp_f32; exact at 0, saturates correctly at +/-inf (no NaN)
__device__ inline float fast_tanh(float x) {
  float e = __expf(2.0f * x);
  return 1.0f - 2.0f / (e + 1.0f);
}

// ---------- casts ----------
__global__ __launch_bounds__(256)
void cast_bf4(const float* __restrict__ src, u16* __restrict__ dst, long long n4) {
  long long i = (long long)blockIdx.x * 256 + threadIdx.x;
  if (i >= n4) return;
  float4 v = ((const float4*)src)[i];
  ushort4 o;
  o.x = f2bf(v.x); o.y = f2bf(v.y); o.z = f2bf(v.z); o.w = f2bf(v.w);
  ((ushort4*)dst)[i] = o;
}
__global__ __launch_bounds__(256)
void cast_split(const float* __restrict__ src, u16* __restrict__ hi,
                u16* __restrict__ lo, long long n) {
  long long i = (long long)blockIdx.x * 256 + threadIdx.x;
  if (i < n) {
    float v = src[i];
    u16 h = f2bf(v);
    hi[i] = h;
    lo[i] = f2bf(v - bf2f(h));
  }
}
// transpose + split: dst[i][j] = split(src[j][i]), 1024x1024
__global__ __launch_bounds__(256)
void transpose_split(const float* __restrict__ src, u16* __restrict__ hi,
                     u16* __restrict__ lo) {
  __shared__ float t[32][33];
  const int bx = blockIdx.x * 32;   // i-base (src col, dst row)
  const int by = blockIdx.y * 32;   // j-base (src row, dst col)
  const int c = threadIdx.x & 31;
  const int r0 = (threadIdx.x >> 5) * 4;
#pragma unroll
  for (int r = 0; r < 4; r++)
    t[r0 + r][c] = src[(long long)(by + r0 + r) * D_MODEL + bx + c];
  __syncthreads();
#pragma unroll
  for (int r = 0; r < 4; r++) {
    float v = t[c][r0 + r];
    long long idx = (long long)(bx + r0 + r) * D_MODEL + by + c;
    u16 h = f2bf(v);
    hi[idx] = h;
    lo[idx] = f2bf(v - bf2f(h));
  }
}
__global__ __launch_bounds__(256)
void zero_stats(float* __restrict__ p, int n) {
  int i = blockIdx.x * 256 + threadIdx.x;
  if (i < n) p[i] = 0.f;
}
// w2b[d] = sum_j Wo[d][j] * bv[j]   (one block per d)
__global__ __launch_bounds__(256)
void w2_bias(const float* __restrict__ Wo, const float* __restrict__ bv,
             float* __restrict__ w2b) {
  const int d = blockIdx.x;
  const int tid = threadIdx.x;
  float acc = 0.f;
  for (int j = tid; j < D_MODEL; j += 256)
    acc += Wo[(long long)d * D_MODEL + j] * bv[j];
#pragma unroll
  for (int m = 1; m < 64; m <<= 1) acc += __shfl_xor(acc, m);
  __shared__ float red[4];
  if ((tid & 63) == 0) red[tid >> 6] = acc;
  __syncthreads();
  if (tid == 0) w2b[d] = red[0] + red[1] + red[2] + red[3];
}

// ============================================================
// Fused Q+K projection: dual-acc NT GEMM sharing the A (=x) staging.
// 2-phase double-buffered pipeline: stage(t+1) issued before compute(t),
// ONE barrier per K-step (was two).
// ============================================================
__global__ __launch_bounds__(256, 2)
void qk_fused(const u16* __restrict__ X, const u16* __restrict__ Wq,
              const u16* __restrict__ Wk,
              const float* __restrict__ bq, const float* __restrict__ bk,
              u16* __restrict__ Qo, u16* __restrict__ Ko) {
  __shared__ u16 Xs[2][128 * 32];
  __shared__ u16 Qs[2][128 * 32];
  __shared__ u16 Ks[2][128 * 32];
  const int tid  = threadIdx.x;
  const int wave = tid >> 6;
  const int lane = tid & 63;
  const int quad = lane >> 4;
  const int tc   = lane & 15;
  const int bm = blockIdx.y * 128;
  const int bn = blockIdx.x * 128;
  const int wm = (wave & 1) * 64;
  const int wn = (wave >> 1) * 64;

  f32x4 acc1[4][4], acc2[4][4];
#pragma unroll
  for (int i = 0; i < 4; i++)
#pragma unroll
    for (int j = 0; j < 4; j++) {
      acc1[i][j] = (f32x4){0.f, 0.f, 0.f, 0.f};
      acc2[i][j] = (f32x4){0.f, 0.f, 0.f, 0.f};
    }

  const int srow = wave * 32 + (lane >> 2);
  const int scol = (lane & 3) * 8;
  const u16* gx = X  + (long long)(bm + srow) * D_MODEL + scol;
  const u16* gq = Wq + (long long)(bn + srow) * D_MODEL + scol;
  const u16* gk = Wk + (long long)(bn + srow) * D_MODEL + scol;
  const int wb = (wave * 32) * 32;
  const long long r16 = 16LL * D_MODEL;

  // prologue: stage tile 0 into buf 0
  gl2lds16(gx,       Xs[0] + wb);
  gl2lds16(gx + r16, Xs[0] + wb + 512);
  gl2lds16(gq,       Qs[0] + wb);
  gl2lds16(gq + r16, Qs[0] + wb + 512);
  gl2lds16(gk,       Ks[0] + wb);
  gl2lds16(gk + r16, Ks[0] + wb + 512);
  gx += 32; gq += 32; gk += 32;
  __syncthreads();

  int cur = 0;
  for (int t = 0; t < 32; ++t) {
    const int nxt = cur ^ 1;
    if (t < 31) {   // issue next-tile loads BEFORE compute of current tile
      gl2lds16(gx,       Xs[nxt] + wb);
      gl2lds16(gx + r16, Xs[nxt] + wb + 512);
      gl2lds16(gq,       Qs[nxt] + wb);
      gl2lds16(gq + r16, Qs[nxt] + wb + 512);
      gl2lds16(gk,       Ks[nxt] + wb);
      gl2lds16(gk + r16, Ks[nxt] + wb + 512);
      gx += 32; gq += 32; gk += 32;
    }
    bf16x8 af[4], bq4[4], bk4[4];
#pragma unroll
    for (int i = 0; i < 4; i++)
      af[i] = *(const bf16x8*)(Xs[cur] + (wm + i * 16 + tc) * 32 + quad * 8);
#pragma unroll
    for (int j = 0; j < 4; j++) {
      int o = (wn + j * 16 + tc) * 32 + quad * 8;
      bq4[j] = *(const bf16x8*)(Qs[cur] + o);
      bk4[j] = *(const bf16x8*)(Ks[cur] + o);
    }
#pragma unroll
    for (int i = 0; i < 4; i++)
#pragma unroll
      for (int j = 0; j < 4; j++) {
        acc1[i][j] = __builtin_amdgcn_mfma_f32_16x16x32_bf16(af[i], bq4[j], acc1[i][j], 0, 0, 0);
        acc2[i][j] = __builtin_amdgcn_mfma_f32_16x16x32_bf16(af[i], bk4[j], acc2[i][j], 0, 0, 0);
      }
    __syncthreads();   // drains stage(t+1) vmcnt + protects buf reuse
    cur = nxt;
  }

#pragma unroll
  for (int i = 0; i < 4; i++) {
    const int row0 = bm + wm + i * 16 + quad * 4;
#pragma unroll
    for (int j = 0; j < 4; j++) {
      const int col = bn + wn + j * 16 + tc;
#pragma unroll
      for (int r = 0; r < 4; r++) {
        long long idx = (long long)(row0 + r) * D_MODEL + col;
        Qo[idx] = f2bf(acc1[i][j][r] + bq[col]);
        Ko[idx] = f2bf(acc2[i][j][r] + bk[col]);
      }
    }
  }
}

// ============================================================
// Fused pfQ+pfK projection: dual-acc NT GEMM sharing the B (=Wp) staging.
// 2-phase double-buffered pipeline.
// ============================================================
__global__ __launch_bounds__(256, 2)
void pf_fused(const u16* __restrict__ Qb, const u16* __restrict__ Wp,
              const float* __restrict__ bp,
              u16* __restrict__ pfQ, u16* __restrict__ pfK,
              long long TDo) {
  __shared__ u16 Qs[2][128 * 32];
  __shared__ u16 Ks[2][128 * 32];
  __shared__ u16 Ws[2][128 * 32];
  const int tid  = threadIdx.x;
  const int wave = tid >> 6;
  const int lane = tid & 63;
  const int quad = lane >> 4;
  const int tc   = lane & 15;
  const int bm = blockIdx.y * 128;
  const int bn = blockIdx.x * 128;
  const int wm = (wave & 1) * 64;
  const int wn = (wave >> 1) * 64;

  f32x4 acc1[4][4], acc2[4][4];
#pragma unroll
  for (int i = 0; i < 4; i++)
#pragma unroll
    for (int j = 0; j < 4; j++) {
      acc1[i][j] = (f32x4){0.f, 0.f, 0.f, 0.f};
      acc2[i][j] = (f32x4){0.f, 0.f, 0.f, 0.f};
    }

  const int srow = wave * 32 + (lane >> 2);
  const int scol = (lane & 3) * 8;
  const u16* gq = Qb + (long long)(bm + srow) * D_MODEL + scol;
  const u16* gk = gq + TDo;
  const u16* gw = Wp + (long long)(bn + srow) * D_MODEL + scol;
  const int wb = (wave * 32) * 32;
  const long long r16 = 16LL * D_MODEL;

  gl2lds16(gq,       Qs[0] + wb);
  gl2lds16(gq + r16, Qs[0] + wb + 512);
  gl2lds16(gk,       Ks[0] + wb);
  gl2lds16(gk + r16, Ks[0] + wb + 512);
  gl2lds16(gw,       Ws[0] + wb);
  gl2lds16(gw + r16, Ws[0] + wb + 512);
  gq += 32; gk += 32; gw += 32;
  __syncthreads();

  int cur = 0;
  for (int t = 0; t < 32; ++t) {
    const int nxt = cur ^ 1;
    if (t < 31) {
      gl2lds16(gq,       Qs[nxt] + wb);
      gl2lds16(gq + r16, Qs[nxt] + wb + 512);
      gl2lds16(gk,       Ks[nxt] + wb);
      gl2lds16(gk + r16, Ks[nxt] + wb + 512);
      gl2lds16(gw,       Ws[nxt] + wb);
      gl2lds16(gw + r16, Ws[nxt] + wb + 512);
      gq += 32; gk += 32; gw += 32;
    }
    bf16x8 aq[4], ak[4], bw[4];
#pragma unroll
    for (int i = 0; i < 4; i++) {
      int o = (wm + i * 16 + tc) * 32 + quad * 8;
      aq[i] = *(const bf16x8*)(Qs[cur] + o);
      ak[i] = *(const bf16x8*)(Ks[cur] + o);
    }
#pragma unroll
    for (int j = 0; j < 4; j++)
      bw[j] = *(const bf16x8*)(Ws[cur] + (wn + j * 16 + tc) * 32 + quad * 8);
#pragma unroll
    for (int i = 0; i < 4; i++)
#pragma unroll
      for (int j = 0; j < 4; j++) {
        acc1[i][j] = __builtin_amdgcn_mfma_f32_16x16x32_bf16(aq[i], bw[j], acc1[i][j], 0, 0, 0);
        acc2[i][j] = __builtin_amdgcn_mfma_f32_16x16x32_bf16(ak[i], bw[j], acc2[i][j], 0, 0, 0);
      }
    __syncthreads();
    cur = nxt;
  }

#pragma unroll
  for (int i = 0; i < 4; i++) {
    const int row0 = bm + wm + i * 16 + quad * 4;
#pragma unroll
    for (int j = 0; j < 4; j++) {
      const int col = bn + wn + j * 16 + tc;
#pragma unroll
      for (int r = 0; r < 4; r++) {
        long long idx = (long long)(row0 + r) * D_MODEL + col;
        float b = bp[col];
        pfQ[idx] = f2bf(acc1[i][j][r] + b);
        pfK[idx] = f2bf(acc2[i][j][r] + b);
      }
    }
  }
}

// ============================================================
// Split-precision GEMM: C = (Ah+Al)(Bh+Bl)^T (+bias), fp32 out.
// 3 MFMAs per frag step (drop Al*Bl). 2-phase pipeline.
// ============================================================
__global__ __launch_bounds__(256)
void mfma_gemm_out3(const u16* __restrict__ Ah, const u16* __restrict__ Al,
                    const u16* __restrict__ Bh, const u16* __restrict__ Bl,
                    const float* __restrict__ bias, float* __restrict__ C,
                    int N, int K) {
  __shared__ u16 Ash[2][128 * 32];
  __shared__ u16 Asl[2][128 * 32];
  __shared__ u16 Bsh[2][128 * 32];
  __shared__ u16 Bsl[2][128 * 32];
  const int tid  = threadIdx.x;
  const int wave = tid >> 6;
  const int lane = tid & 63;
  const int quad = lane >> 4;
  const int tc   = lane & 15;
  const int bm = blockIdx.y * 128;
  const int bn = blockIdx.x * 128;
  const int wm = (wave & 1) * 64;
  const int wn = (wave >> 1) * 64;

  f32x4 acc[4][4];
#pragma unroll
  for (int i = 0; i < 4; i++)
#pragma unroll
    for (int j = 0; j < 4; j++) acc[i][j] = (f32x4){0.f, 0.f, 0.f, 0.f};

  const int srow = wave * 32 + (lane >> 2);
  const int scol = (lane & 3) * 8;
  long long aoff = (long long)(bm + srow) * K + scol;
  long long boff = (long long)(bn + srow) * K + scol;
  const u16 *gah = Ah + aoff, *gal = Al + aoff;
  const u16 *gbh = Bh + boff, *gbl = Bl + boff;
  const int wbase = (wave * 32) * 32;
  const long long r16K = 16LL * K;
  const int NT = K >> 5;

  gl2lds16(gah,        Ash[0] + wbase);
  gl2lds16(gah + r16K, Ash[0] + wbase + 512);
  gl2lds16(gal,        Asl[0] + wbase);
  gl2lds16(gal + r16K, Asl[0] + wbase + 512);
  gl2lds16(gbh,        Bsh[0] + wbase);
  gl2lds16(gbh + r16K, Bsh[0] + wbase + 512);
  gl2lds16(gbl,        Bsl[0] + wbase);
  gl2lds16(gbl + r16K, Bsl[0] + wbase + 512);
  gah += 32; gal += 32; gbh += 32; gbl += 32;
  __syncthreads();

  int cur = 0;
  for (int t = 0; t < NT; ++t) {
    const int nxt = cur ^ 1;
    if (t < NT - 1) {
      gl2lds16(gah,        Ash[nxt] + wbase);
      gl2lds16(gah + r16K, Ash[nxt] + wbase + 512);
      gl2lds16(gal,        Asl[nxt] + wbase);
      gl2lds16(gal + r16K, Asl[nxt] + wbase + 512);
      gl2lds16(gbh,        Bsh[nxt] + wbase);
      gl2lds16(gbh + r16K, Bsh[nxt] + wbase + 512);
      gl2lds16(gbl,        Bsl[nxt] + wbase);
      gl2lds16(gbl + r16K, Bsl[nxt] + wbase + 512);
      gah += 32; gal += 32; gbh += 32; gbl += 32;
    }
    bf16x8 ah[4], al[4], bh[4], bl[4];
#pragma unroll
    for (int i = 0; i < 4; i++) {
      int o = (wm + i * 16 + tc) * 32 + quad * 8;
      ah[i] = *(const bf16x8*)(Ash[cur] + o);
      al[i] = *(const bf16x8*)(Asl[cur] + o);
    }
#pragma unroll
    for (int j = 0; j < 4; j++) {
      int o = (wn + j * 16 + tc) * 32 + quad * 8;
      bh[j] = *(const bf16x8*)(Bsh[cur] + o);
      bl[j] = *(const bf16x8*)(Bsl[cur] + o);
    }
#pragma unroll
    for (int i = 0; i < 4; i++)
#pragma unroll
      for (int j = 0; j < 4; j++) {
        acc[i][j] = __builtin_amdgcn_mfma_f32_16x16x32_bf16(ah[i], bh[j], acc[i][j], 0, 0, 0);
        acc[i][j] = __builtin_amdgcn_mfma_f32_16x16x32_bf16(ah[i], bl[j], acc[i][j], 0, 0, 0);
        acc[i][j] = __builtin_amdgcn_mfma_f32_16x16x32_bf16(al[i], bh[j], acc[i][j], 0, 0, 0);
      }
    __syncthreads();
    cur = nxt;
  }
#pragma unroll
  for (int i = 0; i < 4; i++) {
    const int row0 = bm + wm + i * 16 + quad * 4;
#pragma unroll
    for (int j = 0; j < 4; j++) {
      const int col = bn + wn + j * 16 + tc;
      float b = bias ? bias[col] : 0.f;
#pragma unroll
      for (int r = 0; r < 4; r++)
        C[(long long)(row0 + r) * N + col] = acc[i][j][r] + b;
    }
  }
}

// ============================================================
// VWt[b][d][s] = (W2h+W2l) @ x_b^T + w2b[d], hi/lo bf16 out.
// 2-phase pipeline.
// ============================================================
__global__ __launch_bounds__(256)
void vwt_kernel(const u16* __restrict__ W2h, const u16* __restrict__ W2l,
                const u16* __restrict__ X, const float* __restrict__ w2b,
                u16* __restrict__ Ch, u16* __restrict__ Cl,
                long long sB, long long sC) {
  __shared__ u16 Ah[2][128 * 32];
  __shared__ u16 Al[2][128 * 32];
  __shared__ u16 Bs[2][128 * 32];
  const int tid  = threadIdx.x;
  const int wave = tid >> 6;
  const int lane = tid & 63;
  const int quad = lane >> 4;
  const int tc   = lane & 15;
  const int bm = blockIdx.y * 128;   // d
  const int bn = blockIdx.x * 128;   // s
  const long long z = blockIdx.z;
  const int wm = (wave & 1) * 64;
  const int wn = (wave >> 1) * 64;

  f32x4 acc[4][4];
#pragma unroll
  for (int i = 0; i < 4; i++)
#pragma unroll
    for (int j = 0; j < 4; j++) acc[i][j] = (f32x4){0.f, 0.f, 0.f, 0.f};

  const int srow = wave * 32 + (lane >> 2);
  const int scol = (lane & 3) * 8;
  const long long aoff = (long long)(bm + srow) * D_MODEL + scol;
  const u16* gah = W2h + aoff;
  const u16* gal = W2l + aoff;
  const u16* gb  = X + z * sB + (long long)(bn + srow) * D_MODEL + scol;
  const int wb = (wave * 32) * 32;
  const long long r16 = 16LL * D_MODEL;

  gl2lds16(gah,       Ah[0] + wb);
  gl2lds16(gah + r16, Ah[0] + wb + 512);
  gl2lds16(gal,       Al[0] + wb);
  gl2lds16(gal + r16, Al[0] + wb + 512);
  gl2lds16(gb,        Bs[0] + wb);
  gl2lds16(gb + r16,  Bs[0] + wb + 512);
  gah += 32; gal += 32; gb += 32;
  __syncthreads();

  int cur = 0;
  for (int t = 0; t < 32; ++t) {
    const int nxt = cur ^ 1;
    if (t < 31) {
      gl2lds16(gah,       Ah[nxt] + wb);
      gl2lds16(gah + r16, Ah[nxt] + wb + 512);
      gl2lds16(gal,       Al[nxt] + wb);
      gl2lds16(gal + r16, Al[nxt] + wb + 512);
      gl2lds16(gb,        Bs[nxt] + wb);
      gl2lds16(gb + r16,  Bs[nxt] + wb + 512);
      gah += 32; gal += 32; gb += 32;
    }
    bf16x8 ah4[4], al4[4], bx[4];
#pragma unroll
    for (int i = 0; i < 4; i++) {
      int o = (wm + i * 16 + tc) * 32 + quad * 8;
      ah4[i] = *(const bf16x8*)(Ah[cur] + o);
      al4[i] = *(const bf16x8*)(Al[cur] + o);
    }
#pragma unroll
    for (int j = 0; j < 4; j++)
      bx[j] = *(const bf16x8*)(Bs[cur] + (wn + j * 16 + tc) * 32 + quad * 8);
#pragma unroll
    for (int i = 0; i < 4; i++)
#pragma unroll
      for (int j = 0; j < 4; j++) {
        acc[i][j] = __builtin_amdgcn_mfma_f32_16x16x32_bf16(ah4[i], bx[j], acc[i][j], 0, 0, 0);
        acc[i][j] = __builtin_amdgcn_mfma_f32_16x16x32_bf16(al4[i], bx[j], acc[i][j], 0, 0, 0);
      }
    __syncthreads();
    cur = nxt;
  }

  u16* Chz = Ch + z * sC;
  u16* Clz = Cl + z * sC;
#pragma unroll
  for (int i = 0; i < 4; i++) {
    const int row0 = bm + wm + i * 16 + quad * 4;
#pragma unroll
    for (int j = 0; j < 4; j++) {
      const int col = bn + wn + j * 16 + tc;
#pragma unroll
      for (int r = 0; r < 4; r++) {
        float v = acc[i][j][r] + w2b[row0 + r];
        long long idx = (long long)(row0 + r) * S_LEN + col;
        u16 h = f2bf(v);
        Chz[idx] = h;
        Clz[idx] = f2bf(v - bf2f(h));
      }
    }
  }
}

// ============================================================
// B-split GEMM (out): C = A @ (Bh+Bl)^T + bias[col], fp32 out.
// 2-phase pipeline.
// ============================================================
__global__ __launch_bounds__(256)
void gemm_bsplit(const u16* __restrict__ A,
                 const u16* __restrict__ Bh, const u16* __restrict__ Bl,
                 const float* __restrict__ bias, float* __restrict__ C,
                 int N, int K, long long sA, long long sB, long long sC) {
  __shared__ u16 As[2][128 * 32];
  __shared__ u16 Bsh[2][128 * 32];
  __shared__ u16 Bsl[2][128 * 32];
  const int tid  = threadIdx.x;
  const int wave = tid >> 6;
  const int lane = tid & 63;
  const int quad = lane >> 4;
  const int tc   = lane & 15;
  const int bm = blockIdx.y * 128;
  const int bn = blockIdx.x * 128;
  const long long z = blockIdx.z;
  const int wm = (wave & 1) * 64;
  const int wn = (wave >> 1) * 64;

  f32x4 acc[4][4];
#pragma unroll
  for (int i = 0; i < 4; i++)
#pragma unroll
    for (int j = 0; j < 4; j++) acc[i][j] = (f32x4){0.f, 0.f, 0.f, 0.f};

  const int srow = wave * 32 + (lane >> 2);
  const int scol = (lane & 3) * 8;
  const long long boff = (long long)(bn + srow) * K + scol;
  const u16* ga  = A + z * sA + (long long)(bm + srow) * K + scol;
  const u16* gbh = Bh + z * sB + boff;
  const u16* gbl = Bl + z * sB + boff;
  const int wb = (wave * 32) * 32;
  const long long r16K = 16LL * K;
  const int NT = K >> 5;

  gl2lds16(ga,         As[0] + wb);
  gl2lds16(ga + r16K,  As[0] + wb + 512);
  gl2lds16(gbh,        Bsh[0] + wb);
  gl2lds16(gbh + r16K, Bsh[0] + wb + 512);
  gl2lds16(gbl,        Bsl[0] + wb);
  gl2lds16(gbl + r16K, Bsl[0] + wb + 512);
  ga += 32; gbh += 32; gbl += 32;
  __syncthreads();

  int cur = 0;
  for (int t = 0; t < NT; ++t) {
    const int nxt = cur ^ 1;
    if (t < NT - 1) {
      gl2lds16(ga,         As[nxt] + wb);
      gl2lds16(ga + r16K,  As[nxt] + wb + 512);
      gl2lds16(gbh,        Bsh[nxt] + wb);
      gl2lds16(gbh + r16K, Bsh[nxt] + wb + 512);
      gl2lds16(gbl,        Bsl[nxt] + wb);
      gl2lds16(gbl + r16K, Bsl[nxt] + wb + 512);
      ga += 32; gbh += 32; gbl += 32;
    }
    bf16x8 af[4], bh[4], bl[4];
#pragma unroll
    for (int i = 0; i < 4; i++)
      af[i] = *(const bf16x8*)(As[cur] + (wm + i * 16 + tc) * 32 + quad * 8);
#pragma unroll
    for (int j = 0; j < 4; j++) {
      int o = (wn + j * 16 + tc) * 32 + quad * 8;
      bh[j] = *(const bf16x8*)(Bsh[cur] + o);
      bl[j] = *(const bf16x8*)(Bsl[cur] + o);
    }
#pragma unroll
    for (int i = 0; i < 4; i++)
#pragma unroll
      for (int j = 0; j < 4; j++) {
        acc[i][j] = __builtin_amdgcn_mfma_f32_16x16x32_bf16(af[i], bh[j], acc[i][j], 0, 0, 0);
        acc[i][j] = __builtin_amdgcn_mfma_f32_16x16x32_bf16(af[i], bl[j], acc[i][j], 0, 0, 0);
      }
    __syncthreads();
    cur = nxt;
  }

  float* Cz = C + z * sC;
#pragma unroll
  for (int i = 0; i < 4; i++) {
    const int row0 = bm + wm + i * 16 + quad * 4;
#pragma unroll
    for (int j = 0; j < 4; j++) {
      const int col = bn + wn + j * 16 + tc;
#pragma unroll
      for (int r = 0; r < 4; r++)
        Cz[(long long)(row0 + r) * N + col] = acc[i][j][r] + bias[col];
    }
  }
}

// ============================================================
// Fused chaotic kernel. 2-phase pipeline; epilogue unchanged.
// ============================================================
__global__ __launch_bounds__(256, 2)
void chaotic_fused(const u16* __restrict__ Q, const u16* __restrict__ Kt,
                   const u16* __restrict__ Uq, const u16* __restrict__ Uk,
                   float* __restrict__ Cc,
                   float* __restrict__ ssum, float* __restrict__ ssq,
                   const float* __restrict__ bifp, const float* __restrict__ pcp) {
  __shared__ u16 Qs[2][128 * 32];
  __shared__ u16 Ks[2][128 * 32];
  __shared__ u16 Us[2][128 * 32];
  __shared__ u16 Ws[2][128 * 32];
  const int tid  = threadIdx.x;
  const int wave = tid >> 6;
  const int lane = tid & 63;
  const int quad = lane >> 4;
  const int tc   = lane & 15;
  const int bm = blockIdx.y * 128;
  const int bn = blockIdx.x * 128;
  const long long z = blockIdx.z;
  const long long sQ = (long long)S_LEN * D_MODEL;
  const int wm = (wave & 1) * 64;
  const int wn = (wave >> 1) * 64;

  f32x4 acc1[4][4], acc2[4][4];
#pragma unroll
  for (int i = 0; i < 4; i++)
#pragma unroll
    for (int j = 0; j < 4; j++) {
      acc1[i][j] = (f32x4){0.f, 0.f, 0.f, 0.f};
      acc2[i][j] = (f32x4){0.f, 0.f, 0.f, 0.f};
    }

  const int srow = wave * 32 + (lane >> 2);
  const int scol = (lane & 3) * 8;
  const long long aoff = (long long)(bm + srow) * D_MODEL + scol;
  const long long boff = (long long)(bn + srow) * D_MODEL + scol;
  const u16* gq = Q  + z * sQ + aoff;
  const u16* gk = Kt + z * sQ + boff;
  const u16* gu = Uq + z * sQ + aoff;
  const u16* gw = Uk + z * sQ + boff;
  const int wb = (wave * 32) * 32;
  const long long r16 = 16LL * D_MODEL;

  gl2lds16(gq,       Qs[0] + wb);
  gl2lds16(gq + r16, Qs[0] + wb + 512);
  gl2lds16(gk,       Ks[0] + wb);
  gl2lds16(gk + r16, Ks[0] + wb + 512);
  gl2lds16(gu,       Us[0] + wb);
  gl2lds16(gu + r16, Us[0] + wb + 512);
  gl2lds16(gw,       Ws[0] + wb);
  gl2lds16(gw + r16, Ws[0] + wb + 512);
  gq += 32; gk += 32; gu += 32; gw += 32;
  __syncthreads();

  int cur = 0;
  for (int t = 0; t < 32; ++t) {
    const int nxt = cur ^ 1;
    if (t < 31) {
      gl2lds16(gq,       Qs[nxt] + wb);
      gl2lds16(gq + r16, Qs[nxt] + wb + 512);
      gl2lds16(gk,       Ks[nxt] + wb);
      gl2lds16(gk + r16, Ks[nxt] + wb + 512);
      gl2lds16(gu,       Us[nxt] + wb);
      gl2lds16(gu + r16, Us[nxt] + wb + 512);
      gl2lds16(gw,       Ws[nxt] + wb);
      gl2lds16(gw + r16, Ws[nxt] + wb + 512);
      gq += 32; gk += 32; gu += 32; gw += 32;
    }
    {
      bf16x8 af[4], bg[4];
#pragma unroll
      for (int i = 0; i < 4; i++)
        af[i] = *(const bf16x8*)(Qs[cur] + (wm + i * 16 + tc) * 32 + quad * 8);
#pragma unroll
      for (int j = 0; j < 4; j++)
        bg[j] = *(const bf16x8*)(Ks[cur] + (wn + j * 16 + tc) * 32 + quad * 8);
#pragma unroll
      for (int i = 0; i < 4; i++)
#pragma unroll
        for (int j = 0; j < 4; j++)
          acc1[i][j] = __builtin_amdgcn_mfma_f32_16x16x32_bf16(af[i], bg[j], acc1[i][j], 0, 0, 0);
    }
    {
      bf16x8 cf[4], dg[4];
#pragma unroll
      for (int i = 0; i < 4; i++)
        cf[i] = *(const bf16x8*)(Us[cur] + (wm + i * 16 + tc) * 32 + quad * 8);
#pragma unroll
      for (int j = 0; j < 4; j++)
        dg[j] = *(const bf16x8*)(Ws[cur] + (wn + j * 16 + tc) * 32 + quad * 8);
#pragma unroll
      for (int i = 0; i < 4; i++)
#pragma unroll
        for (int j = 0; j < 4; j++)
          acc2[i][j] = __builtin_amdgcn_mfma_f32_16x16x32_bf16(cf[i], dg[j], acc2[i][j], 0, 0, 0);
    }
    __syncthreads();
    cur = nxt;
  }

  const float bif = *bifp;
  const float pc  = *pcp;
  float rsum[4][4], rsq[4][4];
#pragma unroll
  for (int i = 0; i < 4; i++)
#pragma unroll
    for (int r = 0; r < 4; r++) { rsum[i][r] = 0.f; rsq[i][r] = 0.f; }

  float* C = Cc + z * (long long)S_LEN * S_LEN;
#pragma unroll
  for (int i = 0; i < 4; i++) {
    const int row0 = bm + wm + i * 16 + quad * 4;
#pragma unroll
    for (int j = 0; j < 4; j++) {
      const int col = bn + wn + j * 16 + tc;
#pragma unroll
      for (int r = 0; r < 4; r++) {
        float sc = acc1[i][j][r] * 0.03125f;          // / sqrt(1024)
        float sy = acc2[i][j][r] * (1.0f / 512.0f);   // / HALF
        float t  = fast_tanh(sc);
        C[(long long)(row0 + r) * S_LEN + col] = sc + pc * sy + bif * t * (1.0f - t);
        rsum[i][r] += sy;
        rsq[i][r]  += sy * sy;
      }
    }
  }
#pragma unroll
  for (int m = 1; m < 16; m <<= 1) {
#pragma unroll
    for (int i = 0; i < 4; i++)
#pragma unroll
      for (int r = 0; r < 4; r++) {
        rsum[i][r] += __shfl_xor(rsum[i][r], m);
        rsq[i][r]  += __shfl_xor(rsq[i][r], m);
      }
  }
  if (tc == 0) {
#pragma unroll
    for (int i = 0; i < 4; i++)
#pragma unroll
      for (int r = 0; r < 4; r++) {
        long long rr = z * S_LEN + bm + wm + i * 16 + quad * 4 + r;
        atomicAdd(&ssum[rr], rsum[i][r]);
        atomicAdd(&ssq[rr],  rsq[i][r]);
      }
  }
}

// ============================================================
// Phase normalize in place on dense bf16 pf rows (stride 1024).
// Vectorized: bf16x8 loads/stores (16B/lane) instead of scalar u16.
// ============================================================
__global__ __launch_bounds__(256)
void phase_norm_bf(u16* __restrict__ U, long long n_rows) {
  long long idx = (long long)blockIdx.x * 256 + threadIdx.x;
  if (idx >= n_rows * 64) return;          // 64 threads per row, 8 pairs each
  long long row = idx >> 6;
  int j0 = (int)(idx & 63) * 8;
  u16* p = U + row * D_MODEL + j0;
  bf16x8 re8 = *(const bf16x8*)p;
  bf16x8 im8 = *(const bf16x8*)(p + N_HALF);
  bf16x8 ro, io;
#pragma unroll
  for (int i = 0; i < 8; i++) {
    float re = bf2f((u16)re8[i]);
    float im = bf2f((u16)im8[i]);
    float n2 = re * re + im * im;
    float cr = 1.f, sr = 0.f;
    if (n2 > 0.f) {
      float inv = 1.0f / sqrtf(n2);
      cr = re * inv; sr = im * inv;
    }
    ro[i] = (short)f2bf(cr);
    io[i] = (short)f2bf(sr);
  }
  *(bf16x8*)p = ro;
  *(bf16x8*)(p + N_HALF) = io;
}

// ============================================================
// Row softmax: fp32 in (chaotic), bf16 out (attn). 1 block / row.
// ============================================================
__global__ __launch_bounds__(256)
void softmax_bf(const float* __restrict__ Cc, u16* __restrict__ P) {
  const long long row = (long long)blockIdx.y * S_LEN + blockIdx.x;
  const float* p = Cc + row * S_LEN;
  u16* q = P + row * S_LEN;
  const int tid = threadIdx.x;
  float v[8];
  float m = -3.402823466e+38f;
#pragma unroll
  for (int i = 0; i < 8; i++) { v[i] = p[tid + i * 256]; m = fmaxf(m, v[i]); }
#pragma unroll
  for (int mask = 1; mask < 64; mask <<= 1) m = fmaxf(m, __shfl_xor(m, mask));
  __shared__ float red[8];
  if ((tid & 63) == 0) red[tid >> 6] = m;
  __syncthreads();
  m = fmaxf(fmaxf(red[0], red[1]), fmaxf(red[2], red[3]));
  float s = 0.f;
#pragma unroll
  for (int i = 0; i < 8; i++) { v[i] = __expf(v[i] - m); s += v[i]; }
#pragma unroll
  for (int mask = 1; mask < 64; mask <<= 1) s += __shfl_xor(s, mask);
  __syncthreads();
  if ((tid & 63) == 0) red[4 + (tid >> 6)] = s;
  __syncthreads();
  s = red[4] + red[5] + red[6] + red[7];
  float inv = 1.0f / s;
#pragma unroll
  for (int i = 0; i < 8; i++) q[tid + i * 256] = f2bf(v[i] * inv);
}

// ============================================================
// sync_loss
// ============================================================
__global__ __launch_bounds__(1024)
void syncloss_kernel(const float* __restrict__ ssum, const float* __restrict__ ssq,
                     float* __restrict__ out) {
  const int tid = threadIdx.x;
  float acc = 0.f;
  for (int r = tid; r < N_BATCH * S_LEN; r += 1024) {
    float su = ssum[r], sq = ssq[r];
    acc += (sq - su * su * (1.0f / 2048.0f)) * (1.0f / 2047.0f);
  }
#pragma unroll
  for (int mask = 1; mask < 64; mask <<= 1) acc += __shfl_xor(acc, mask);
  __shared__ float red[16];
  if ((tid & 63) == 0) red[tid >> 6] = acc;
  __syncthreads();
  if (tid == 0) {
    float t = 0.f;
#pragma unroll
    for (int k = 0; k < 16; k++) t += red[k];
    out[0] = 0.01f * (t / (float)(N_BATCH * S_LEN));
  }
}

extern "C" void kernel_launch(void* const* d_in, const int* in_sizes, int n_in,
                              void* d_out, int out_size, void* d_ws, size_t ws_size,
                              hipStream_t stream) {
  const float* x    = (const float*)d_in[0];
  const float* Wq   = (const float*)d_in[1];
  const float* bq   = (const float*)d_in[2];
  const float* Wk   = (const float*)d_in[3];
  const float* bk   = (const float*)d_in[4];
  const float* Wv   = (const float*)d_in[5];
  const float* bv   = (const float*)d_in[6];
  const float* Wp   = (const float*)d_in[7];
  const float* bp   = (const float*)d_in[8];
  const float* Wo   = (const float*)d_in[9];
  const float* bo   = (const float*)d_in[10];
  const float* bifp = (const float*)d_in[11];
  const float* pcp  = (const float*)d_in[12];
  float* out = (float*)d_out;

  const long long NROW = (long long)N_BATCH * S_LEN;   // 8192
  const long long TD   = NROW * D_MODEL;               // 8,388,608
  const long long WSZ  = (long long)D_MODEL * D_MODEL; // 1,048,576

  // workspace layout (~171 MB)
  u16* xbf   = (u16*)d_ws;          // TD
  u16* wqb   = xbf + TD;            // WSZ
  u16* wkb   = wqb + WSZ;           // WSZ
  u16* wpb   = wkb + WSZ;           // WSZ
  u16* woh   = wpb + WSZ;           // WSZ (Wo hi/lo)
  u16* wol   = woh + WSZ;
  u16* wvth  = wol + WSZ;           // WSZ (Wv^T hi/lo)
  u16* wvtl  = wvth + WSZ;
  u16* w2h   = wvtl + WSZ;          // WSZ (W2 hi/lo)
  u16* w2l   = w2h + WSZ;
  float* W2f = (float*)(w2l + WSZ); // WSZ floats (4 MB)
  float* w2b = W2f + WSZ;           // 1024 floats
  u16* Qbf   = (u16*)(w2b + D_MODEL); // TD
  u16* Kbf   = Qbf + TD;            // TD (contiguous)
  u16* pfQ   = Kbf + TD;            // TD
  u16* pfK   = pfQ + TD;            // TD (contiguous)
  float* Cc  = (float*)(pfK + TD);  // B*S*S fp32 (67 MB)
  float* ssum = Cc + (long long)N_BATCH * S_LEN * S_LEN;
  float* ssq  = ssum + NROW;
  u16* attn = Qbf;                  // overlays Q+K after chaotic (2*TD)
  u16* vwh  = pfQ;                  // overlays Uq after chaotic
  u16* vwl  = pfK;                  // overlays Uk after chaotic

  dim3 blk(256);
  const long long sQ = (long long)S_LEN * D_MODEL;   // 2048*1024
  const long long sS = (long long)S_LEN * S_LEN;

  // ---- casts & W2 precompute ----
  cast_bf4<<<(int)(TD / 4 / 256), blk, 0, stream>>>(x, xbf, TD / 4);
  cast_bf4<<<(int)(WSZ / 4 / 256), blk, 0, stream>>>(Wq, wqb, WSZ / 4);
  cast_bf4<<<(int)(WSZ / 4 / 256), blk, 0, stream>>>(Wk, wkb, WSZ / 4);
  cast_bf4<<<(int)(WSZ / 4 / 256), blk, 0, stream>>>(Wp, wpb, WSZ / 4);
  cast_split<<<(int)(WSZ / 256), blk, 0, stream>>>(Wo, woh, wol, WSZ);
  transpose_split<<<dim3(32, 32), blk, 0, stream>>>(Wv, wvth, wvtl);
  // W2 = split(Wo) @ split(Wv^T)^T  (fp32), then split; w2b = Wo @ bv
  mfma_gemm_out3<<<dim3(8, 8, 1), blk, 0, stream>>>(
      woh, wol, wvth, wvtl, nullptr, W2f, D_MODEL, D_MODEL);
  cast_split<<<(int)(WSZ / 256), blk, 0, stream>>>(W2f, w2h, w2l, WSZ);
  w2_bias<<<D_MODEL, blk, 0, stream>>>(Wo, bv, w2b);

  // ---- Q,K fused projection ----
  qk_fused<<<dim3(8, 64), blk, 0, stream>>>(xbf, wqb, wkb, bq, bk, Qbf, Kbf);
  // ---- pfQ,pfK fused projection ----
  pf_fused<<<dim3(8, 64), blk, 0, stream>>>(Qbf, wpb, bp, pfQ, pfK, TD);
  phase_norm_bf<<<(int)(2 * NROW * 64 / 256), blk, 0, stream>>>(pfQ, 2 * NROW);
  zero_stats<<<(int)((2 * NROW + 255) / 256), blk, 0, stream>>>(ssum, (int)(2 * NROW));

  // ---- fused scores + sync + chaotic ----
  chaotic_fused<<<dim3(16, 16, N_BATCH), blk, 0, stream>>>(
      Qbf, Kbf, pfQ, pfK, Cc, ssum, ssq, bifp, pcp);
  // ---- VWt = split(W2) @ x_b^T + w2b (overlays pf, dead after chaotic) ----
  vwt_kernel<<<dim3(16, 8, N_BATCH), blk, 0, stream>>>(
      w2h, w2l, xbf, w2b, vwh, vwl, sQ, sQ);
  // ---- softmax (overlays Q/K) ----
  softmax_bf<<<dim3(S_LEN, N_BATCH), blk, 0, stream>>>(Cc, attn);
  // ---- out = attn @ (VWth+VWtl)^T + bo ----
  gemm_bsplit<<<dim3(8, 16, N_BATCH), blk, 0, stream>>>(
      attn, vwh, vwl, bo, out,
      D_MODEL, S_LEN, sS, sQ, sQ);
  // ---- sync_loss ----
  syncloss_kernel<<<1, 1024, 0, stream>>>(ssum, ssq, out + TD);
}

// Round 2
// 507.330 us; speedup vs baseline: 1.1135x; 1.1135x over previous
//
#include <hip/hip_runtime.h>
#include <hip/hip_bf16.h>
#include <math.h>

#define S_LEN 2048
#define D_MODEL 1024
#define N_BATCH 4
#define N_HALF 512

typedef unsigned short u16;
typedef __attribute__((ext_vector_type(8))) short bf16x8;
typedef __attribute__((ext_vector_type(4))) float f32x4;

// ---------- helpers ----------
__device__ inline u16 f2bf(float v) {
  __hip_bfloat16 h = __float2bfloat16(v);   // RNE
  return *reinterpret_cast<u16*>(&h);
}
__device__ inline float bf2f(u16 u) {
  __hip_bfloat16 h = *reinterpret_cast<__hip_bfloat16*>(&u);
  return __bfloat162float(h);
}
// async global->LDS, 16B per lane; LDS dest is wave-uniform base + lane*16
__device__ inline void gl2lds16(const void* g, void* l) {
  __builtin_amdgcn_global_load_lds(
      (const __attribute__((address_space(1))) unsigned int*)g,
      (__attribute__((address_space(3))) unsigned int*)l, 16, 0, 0);
}
// tanh via v_exp_f32; exact at 0, saturates correctly at +/-inf (no NaN)
__device__ inline float fast_tanh(float x) {
  float e = __expf(2.0f * x);
  return 1.0f - 2.0f / (e + 1.0f);
}

// ---------- casts ----------
__global__ __launch_bounds__(256)
void cast_bf4(const float* __restrict__ src, u16* __restrict__ dst, long long n4) {
  long long i = (long long)blockIdx.x * 256 + threadIdx.x;
  if (i >= n4) return;
  float4 v = ((const float4*)src)[i];
  ushort4 o;
  o.x = f2bf(v.x); o.y = f2bf(v.y); o.z = f2bf(v.z); o.w = f2bf(v.w);
  ((ushort4*)dst)[i] = o;
}
__global__ __launch_bounds__(256)
void cast_split(const float* __restrict__ src, u16* __restrict__ hi,
                u16* __restrict__ lo, long long n) {
  long long i = (long long)blockIdx.x * 256 + threadIdx.x;
  if (i < n) {
    float v = src[i];
    u16 h = f2bf(v);
    hi[i] = h;
    lo[i] = f2bf(v - bf2f(h));
  }
}
// transpose + split: dst[i][j] = split(src[j][i]), 1024x1024
__global__ __launch_bounds__(256)
void transpose_split(const float* __restrict__ src, u16* __restrict__ hi,
                     u16* __restrict__ lo) {
  __shared__ float t[32][33];
  const int bx = blockIdx.x * 32;   // i-base (src col, dst row)
  const int by = blockIdx.y * 32;   // j-base (src row, dst col)
  const int c = threadIdx.x & 31;
  const int r0 = (threadIdx.x >> 5) * 4;
#pragma unroll
  for (int r = 0; r < 4; r++)
    t[r0 + r][c] = src[(long long)(by + r0 + r) * D_MODEL + bx + c];
  __syncthreads();
#pragma unroll
  for (int r = 0; r < 4; r++) {
    float v = t[c][r0 + r];
    long long idx = (long long)(bx + r0 + r) * D_MODEL + by + c;
    u16 h = f2bf(v);
    hi[idx] = h;
    lo[idx] = f2bf(v - bf2f(h));
  }
}
__global__ __launch_bounds__(256)
void zero_stats(float* __restrict__ p, int n) {
  int i = blockIdx.x * 256 + threadIdx.x;
  if (i < n) p[i] = 0.f;
}
// w2b[d] = sum_j Wo[d][j] * bv[j]   (one block per d)
__global__ __launch_bounds__(256)
void w2_bias(const float* __restrict__ Wo, const float* __restrict__ bv,
             float* __restrict__ w2b) {
  const int d = blockIdx.x;
  const int tid = threadIdx.x;
  float acc = 0.f;
  for (int j = tid; j < D_MODEL; j += 256)
    acc += Wo[(long long)d * D_MODEL + j] * bv[j];
#pragma unroll
  for (int m = 1; m < 64; m <<= 1) acc += __shfl_xor(acc, m);
  __shared__ float red[4];
  if ((tid & 63) == 0) red[tid >> 6] = acc;
  __syncthreads();
  if (tid == 0) w2b[d] = red[0] + red[1] + red[2] + red[3];
}

// ============================================================
// Fused Q+K projection: dual-acc NT GEMM sharing the A (=x) staging.
//   (round-0 single-buffer body — proven fastest)
// ============================================================
__global__ __launch_bounds__(256, 2)
void qk_fused(const u16* __restrict__ X, const u16* __restrict__ Wq,
              const u16* __restrict__ Wk,
              const float* __restrict__ bq, const float* __restrict__ bk,
              u16* __restrict__ Qo, u16* __restrict__ Ko) {
  __shared__ u16 Xs[128 * 32];
  __shared__ u16 Qs[128 * 32];
  __shared__ u16 Ks[128 * 32];
  const int tid  = threadIdx.x;
  const int wave = tid >> 6;
  const int lane = tid & 63;
  const int quad = lane >> 4;
  const int tc   = lane & 15;
  const int bm = blockIdx.y * 128;
  const int bn = blockIdx.x * 128;
  const int wm = (wave & 1) * 64;
  const int wn = (wave >> 1) * 64;

  f32x4 acc1[4][4], acc2[4][4];
#pragma unroll
  for (int i = 0; i < 4; i++)
#pragma unroll
    for (int j = 0; j < 4; j++) {
      acc1[i][j] = (f32x4){0.f, 0.f, 0.f, 0.f};
      acc2[i][j] = (f32x4){0.f, 0.f, 0.f, 0.f};
    }

  const int srow = wave * 32 + (lane >> 2);
  const int scol = (lane & 3) * 8;
  const u16* gx = X  + (long long)(bm + srow) * D_MODEL + scol;
  const u16* gq = Wq + (long long)(bn + srow) * D_MODEL + scol;
  const u16* gk = Wk + (long long)(bn + srow) * D_MODEL + scol;
  const int wb = (wave * 32) * 32;
  const long long r16 = 16LL * D_MODEL;

  for (int k0 = 0; k0 < D_MODEL; k0 += 32) {
    gl2lds16(gx,       Xs + wb);
    gl2lds16(gx + r16, Xs + wb + 512);
    gl2lds16(gq,       Qs + wb);
    gl2lds16(gq + r16, Qs + wb + 512);
    gl2lds16(gk,       Ks + wb);
    gl2lds16(gk + r16, Ks + wb + 512);
    gx += 32; gq += 32; gk += 32;
    __syncthreads();
    bf16x8 af[4], bq4[4], bk4[4];
#pragma unroll
    for (int i = 0; i < 4; i++)
      af[i] = *(const bf16x8*)(Xs + (wm + i * 16 + tc) * 32 + quad * 8);
#pragma unroll
    for (int j = 0; j < 4; j++) {
      int o = (wn + j * 16 + tc) * 32 + quad * 8;
      bq4[j] = *(const bf16x8*)(Qs + o);
      bk4[j] = *(const bf16x8*)(Ks + o);
    }
#pragma unroll
    for (int i = 0; i < 4; i++)
#pragma unroll
      for (int j = 0; j < 4; j++) {
        acc1[i][j] = __builtin_amdgcn_mfma_f32_16x16x32_bf16(af[i], bq4[j], acc1[i][j], 0, 0, 0);
        acc2[i][j] = __builtin_amdgcn_mfma_f32_16x16x32_bf16(af[i], bk4[j], acc2[i][j], 0, 0, 0);
      }
    __syncthreads();
  }

#pragma unroll
  for (int i = 0; i < 4; i++) {
    const int row0 = bm + wm + i * 16 + quad * 4;
#pragma unroll
    for (int j = 0; j < 4; j++) {
      const int col = bn + wn + j * 16 + tc;
#pragma unroll
      for (int r = 0; r < 4; r++) {
        long long idx = (long long)(row0 + r) * D_MODEL + col;
        Qo[idx] = f2bf(acc1[i][j][r] + bq[col]);
        Ko[idx] = f2bf(acc2[i][j][r] + bk[col]);
      }
    }
  }
}

// ============================================================
// Fused pfQ+pfK projection (round-0 single-buffer body).
// ============================================================
__global__ __launch_bounds__(256, 2)
void pf_fused(const u16* __restrict__ Qb, const u16* __restrict__ Wp,
              const float* __restrict__ bp,
              u16* __restrict__ pfQ, u16* __restrict__ pfK,
              long long TDo) {
  __shared__ u16 Qs[128 * 32];
  __shared__ u16 Ks[128 * 32];
  __shared__ u16 Ws[128 * 32];
  const int tid  = threadIdx.x;
  const int wave = tid >> 6;
  const int lane = tid & 63;
  const int quad = lane >> 4;
  const int tc   = lane & 15;
  const int bm = blockIdx.y * 128;
  const int bn = blockIdx.x * 128;
  const int wm = (wave & 1) * 64;
  const int wn = (wave >> 1) * 64;

  f32x4 acc1[4][4], acc2[4][4];
#pragma unroll
  for (int i = 0; i < 4; i++)
#pragma unroll
    for (int j = 0; j < 4; j++) {
      acc1[i][j] = (f32x4){0.f, 0.f, 0.f, 0.f};
      acc2[i][j] = (f32x4){0.f, 0.f, 0.f, 0.f};
    }

  const int srow = wave * 32 + (lane >> 2);
  const int scol = (lane & 3) * 8;
  const u16* gq = Qb + (long long)(bm + srow) * D_MODEL + scol;
  const u16* gk = gq + TDo;
  const u16* gw = Wp + (long long)(bn + srow) * D_MODEL + scol;
  const int wb = (wave * 32) * 32;
  const long long r16 = 16LL * D_MODEL;

  for (int k0 = 0; k0 < D_MODEL; k0 += 32) {
    gl2lds16(gq,       Qs + wb);
    gl2lds16(gq + r16, Qs + wb + 512);
    gl2lds16(gk,       Ks + wb);
    gl2lds16(gk + r16, Ks + wb + 512);
    gl2lds16(gw,       Ws + wb);
    gl2lds16(gw + r16, Ws + wb + 512);
    gq += 32; gk += 32; gw += 32;
    __syncthreads();
    bf16x8 aq[4], ak[4], bw[4];
#pragma unroll
    for (int i = 0; i < 4; i++) {
      int o = (wm + i * 16 + tc) * 32 + quad * 8;
      aq[i] = *(const bf16x8*)(Qs + o);
      ak[i] = *(const bf16x8*)(Ks + o);
    }
#pragma unroll
    for (int j = 0; j < 4; j++)
      bw[j] = *(const bf16x8*)(Ws + (wn + j * 16 + tc) * 32 + quad * 8);
#pragma unroll
    for (int i = 0; i < 4; i++)
#pragma unroll
      for (int j = 0; j < 4; j++) {
        acc1[i][j] = __builtin_amdgcn_mfma_f32_16x16x32_bf16(aq[i], bw[j], acc1[i][j], 0, 0, 0);
        acc2[i][j] = __builtin_amdgcn_mfma_f32_16x16x32_bf16(ak[i], bw[j], acc2[i][j], 0, 0, 0);
      }
    __syncthreads();
  }

#pragma unroll
  for (int i = 0; i < 4; i++) {
    const int row0 = bm + wm + i * 16 + quad * 4;
#pragma unroll
    for (int j = 0; j < 4; j++) {
      const int col = bn + wn + j * 16 + tc;
#pragma unroll
      for (int r = 0; r < 4; r++) {
        long long idx = (long long)(row0 + r) * D_MODEL + col;
        float b = bp[col];
        pfQ[idx] = f2bf(acc1[i][j][r] + b);
        pfK[idx] = f2bf(acc2[i][j][r] + b);
      }
    }
  }
}

// ============================================================
// Split-precision GEMM: C = (Ah+Al)(Bh+Bl)^T (+bias), fp32 out.
// (round-0 single-buffer body)
// ============================================================
__global__ __launch_bounds__(256)
void mfma_gemm_out3(const u16* __restrict__ Ah, const u16* __restrict__ Al,
                    const u16* __restrict__ Bh, const u16* __restrict__ Bl,
                    const float* __restrict__ bias, float* __restrict__ C,
                    int N, int K) {
  __shared__ u16 Ash[128 * 32];
  __shared__ u16 Asl[128 * 32];
  __shared__ u16 Bsh[128 * 32];
  __shared__ u16 Bsl[128 * 32];
  const int tid  = threadIdx.x;
  const int wave = tid >> 6;
  const int lane = tid & 63;
  const int quad = lane >> 4;
  const int tc   = lane & 15;
  const int bm = blockIdx.y * 128;
  const int bn = blockIdx.x * 128;
  const int wm = (wave & 1) * 64;
  const int wn = (wave >> 1) * 64;

  f32x4 acc[4][4];
#pragma unroll
  for (int i = 0; i < 4; i++)
#pragma unroll
    for (int j = 0; j < 4; j++) acc[i][j] = (f32x4){0.f, 0.f, 0.f, 0.f};

  const int srow = wave * 32 + (lane >> 2);
  const int scol = (lane & 3) * 8;
  long long aoff = (long long)(bm + srow) * K + scol;
  long long boff = (long long)(bn + srow) * K + scol;
  const u16 *gah = Ah + aoff, *gal = Al + aoff;
  const u16 *gbh = Bh + boff, *gbl = Bl + boff;
  const int wbase = (wave * 32) * 32;
  const long long r16K = 16LL * K;

  for (int k0 = 0; k0 < K; k0 += 32) {
    gl2lds16(gah,        Ash + wbase);
    gl2lds16(gah + r16K, Ash + wbase + 512);
    gl2lds16(gal,        Asl + wbase);
    gl2lds16(gal + r16K, Asl + wbase + 512);
    gl2lds16(gbh,        Bsh + wbase);
    gl2lds16(gbh + r16K, Bsh + wbase + 512);
    gl2lds16(gbl,        Bsl + wbase);
    gl2lds16(gbl + r16K, Bsl + wbase + 512);
    gah += 32; gal += 32; gbh += 32; gbl += 32;
    __syncthreads();
    bf16x8 ah[4], al[4], bh[4], bl[4];
#pragma unroll
    for (int i = 0; i < 4; i++) {
      int o = (wm + i * 16 + tc) * 32 + quad * 8;
      ah[i] = *(const bf16x8*)(Ash + o);
      al[i] = *(const bf16x8*)(Asl + o);
    }
#pragma unroll
    for (int j = 0; j < 4; j++) {
      int o = (wn + j * 16 + tc) * 32 + quad * 8;
      bh[j] = *(const bf16x8*)(Bsh + o);
      bl[j] = *(const bf16x8*)(Bsl + o);
    }
#pragma unroll
    for (int i = 0; i < 4; i++)
#pragma unroll
      for (int j = 0; j < 4; j++) {
        acc[i][j] = __builtin_amdgcn_mfma_f32_16x16x32_bf16(ah[i], bh[j], acc[i][j], 0, 0, 0);
        acc[i][j] = __builtin_amdgcn_mfma_f32_16x16x32_bf16(ah[i], bl[j], acc[i][j], 0, 0, 0);
        acc[i][j] = __builtin_amdgcn_mfma_f32_16x16x32_bf16(al[i], bh[j], acc[i][j], 0, 0, 0);
      }
    __syncthreads();
  }
#pragma unroll
  for (int i = 0; i < 4; i++) {
    const int row0 = bm + wm + i * 16 + quad * 4;
#pragma unroll
    for (int j = 0; j < 4; j++) {
      const int col = bn + wn + j * 16 + tc;
      float b = bias ? bias[col] : 0.f;
#pragma unroll
      for (int r = 0; r < 4; r++)
        C[(long long)(row0 + r) * N + col] = acc[i][j][r] + b;
    }
  }
}

// ============================================================
// VWt[b][d][s] = (W2h+W2l) @ x_b^T + w2b[d], hi/lo bf16 out.
// (round-0 single-buffer body)
// ============================================================
__global__ __launch_bounds__(256)
void vwt_kernel(const u16* __restrict__ W2h, const u16* __restrict__ W2l,
                const u16* __restrict__ X, const float* __restrict__ w2b,
                u16* __restrict__ Ch, u16* __restrict__ Cl,
                long long sB, long long sC) {
  __shared__ u16 Ah[128 * 32];
  __shared__ u16 Al[128 * 32];
  __shared__ u16 Bs[128 * 32];
  const int tid  = threadIdx.x;
  const int wave = tid >> 6;
  const int lane = tid & 63;
  const int quad = lane >> 4;
  const int tc   = lane & 15;
  const int bm = blockIdx.y * 128;   // d
  const int bn = blockIdx.x * 128;   // s
  const long long z = blockIdx.z;
  const int wm = (wave & 1) * 64;
  const int wn = (wave >> 1) * 64;

  f32x4 acc[4][4];
#pragma unroll
  for (int i = 0; i < 4; i++)
#pragma unroll
    for (int j = 0; j < 4; j++) acc[i][j] = (f32x4){0.f, 0.f, 0.f, 0.f};

  const int srow = wave * 32 + (lane >> 2);
  const int scol = (lane & 3) * 8;
  const long long aoff = (long long)(bm + srow) * D_MODEL + scol;
  const u16* gah = W2h + aoff;
  const u16* gal = W2l + aoff;
  const u16* gb  = X + z * sB + (long long)(bn + srow) * D_MODEL + scol;
  const int wb = (wave * 32) * 32;
  const long long r16 = 16LL * D_MODEL;

  for (int k0 = 0; k0 < D_MODEL; k0 += 32) {
    gl2lds16(gah,       Ah + wb);
    gl2lds16(gah + r16, Ah + wb + 512);
    gl2lds16(gal,       Al + wb);
    gl2lds16(gal + r16, Al + wb + 512);
    gl2lds16(gb,        Bs + wb);
    gl2lds16(gb + r16,  Bs + wb + 512);
    gah += 32; gal += 32; gb += 32;
    __syncthreads();
    bf16x8 ah4[4], al4[4], bx[4];
#pragma unroll
    for (int i = 0; i < 4; i++) {
      int o = (wm + i * 16 + tc) * 32 + quad * 8;
      ah4[i] = *(const bf16x8*)(Ah + o);
      al4[i] = *(const bf16x8*)(Al + o);
    }
#pragma unroll
    for (int j = 0; j < 4; j++)
      bx[j] = *(const bf16x8*)(Bs + (wn + j * 16 + tc) * 32 + quad * 8);
#pragma unroll
    for (int i = 0; i < 4; i++)
#pragma unroll
      for (int j = 0; j < 4; j++) {
        acc[i][j] = __builtin_amdgcn_mfma_f32_16x16x32_bf16(ah4[i], bx[j], acc[i][j], 0, 0, 0);
        acc[i][j] = __builtin_amdgcn_mfma_f32_16x16x32_bf16(al4[i], bx[j], acc[i][j], 0, 0, 0);
      }
    __syncthreads();
  }

  u16* Chz = Ch + z * sC;
  u16* Clz = Cl + z * sC;
#pragma unroll
  for (int i = 0; i < 4; i++) {
    const int row0 = bm + wm + i * 16 + quad * 4;
#pragma unroll
    for (int j = 0; j < 4; j++) {
      const int col = bn + wn + j * 16 + tc;
#pragma unroll
      for (int r = 0; r < 4; r++) {
        float v = acc[i][j][r] + w2b[row0 + r];
        long long idx = (long long)(row0 + r) * S_LEN + col;
        u16 h = f2bf(v);
        Chz[idx] = h;
        Clz[idx] = f2bf(v - bf2f(h));
      }
    }
  }
}

// ============================================================
// B-split GEMM (out): C = A @ (Bh+Bl)^T + bias[col], fp32 out.
// (round-0 single-buffer body)
// ============================================================
__global__ __launch_bounds__(256)
void gemm_bsplit(const u16* __restrict__ A,
                 const u16* __restrict__ Bh, const u16* __restrict__ Bl,
                 const float* __restrict__ bias, float* __restrict__ C,
                 int N, int K, long long sA, long long sB, long long sC) {
  __shared__ u16 As[128 * 32];
  __shared__ u16 Bsh[128 * 32];
  __shared__ u16 Bsl[128 * 32];
  const int tid  = threadIdx.x;
  const int wave = tid >> 6;
  const int lane = tid & 63;
  const int quad = lane >> 4;
  const int tc   = lane & 15;
  const int bm = blockIdx.y * 128;
  const int bn = blockIdx.x * 128;
  const long long z = blockIdx.z;
  const int wm = (wave & 1) * 64;
  const int wn = (wave >> 1) * 64;

  f32x4 acc[4][4];
#pragma unroll
  for (int i = 0; i < 4; i++)
#pragma unroll
    for (int j = 0; j < 4; j++) acc[i][j] = (f32x4){0.f, 0.f, 0.f, 0.f};

  const int srow = wave * 32 + (lane >> 2);
  const int scol = (lane & 3) * 8;
  const long long boff = (long long)(bn + srow) * K + scol;
  const u16* ga  = A + z * sA + (long long)(bm + srow) * K + scol;
  const u16* gbh = Bh + z * sB + boff;
  const u16* gbl = Bl + z * sB + boff;
  const int wb = (wave * 32) * 32;
  const long long r16K = 16LL * K;

  for (int k0 = 0; k0 < K; k0 += 32) {
    gl2lds16(ga,         As + wb);
    gl2lds16(ga + r16K,  As + wb + 512);
    gl2lds16(gbh,        Bsh + wb);
    gl2lds16(gbh + r16K, Bsh + wb + 512);
    gl2lds16(gbl,        Bsl + wb);
    gl2lds16(gbl + r16K, Bsl + wb + 512);
    ga += 32; gbh += 32; gbl += 32;
    __syncthreads();
    bf16x8 af[4], bh[4], bl[4];
#pragma unroll
    for (int i = 0; i < 4; i++)
      af[i] = *(const bf16x8*)(As + (wm + i * 16 + tc) * 32 + quad * 8);
#pragma unroll
    for (int j = 0; j < 4; j++) {
      int o = (wn + j * 16 + tc) * 32 + quad * 8;
      bh[j] = *(const bf16x8*)(Bsh + o);
      bl[j] = *(const bf16x8*)(Bsl + o);
    }
#pragma unroll
    for (int i = 0; i < 4; i++)
#pragma unroll
      for (int j = 0; j < 4; j++) {
        acc[i][j] = __builtin_amdgcn_mfma_f32_16x16x32_bf16(af[i], bh[j], acc[i][j], 0, 0, 0);
        acc[i][j] = __builtin_amdgcn_mfma_f32_16x16x32_bf16(af[i], bl[j], acc[i][j], 0, 0, 0);
      }
    __syncthreads();
  }

  float* Cz = C + z * sC;
#pragma unroll
  for (int i = 0; i < 4; i++) {
    const int row0 = bm + wm + i * 16 + quad * 4;
#pragma unroll
    for (int j = 0; j < 4; j++) {
      const int col = bn + wn + j * 16 + tc;
#pragma unroll
      for (int r = 0; r < 4; r++)
        Cz[(long long)(row0 + r) * N + col] = acc[i][j][r] + bias[col];
    }
  }
}

// ============================================================
// Fused chaotic kernel — BK=64 + XOR-swizzled LDS.
//   LDS: 4 x [128][64] u16 = 64 KB, single-buffered (2 blocks/CU unchanged).
//   16 K-iters (was 32) -> half the stage/drain/barrier overhead.
//   Swizzle (rule #21, both sides): LDS stays linear for gl2lds; the
//   per-lane GLOBAL source col is pre-swizzled (c16 ^= row&7), and reads
//   apply the same XOR -> 2-way banks (free) instead of 8/16-way.
// ============================================================
__global__ __launch_bounds__(256, 2)
void chaotic_fused(const u16* __restrict__ Q, const u16* __restrict__ Kt,
                   const u16* __restrict__ Uq, const u16* __restrict__ Uk,
                   float* __restrict__ Cc,
                   float* __restrict__ ssum, float* __restrict__ ssq,
                   const float* __restrict__ bifp, const float* __restrict__ pcp) {
  __shared__ u16 Qs[128 * 64];
  __shared__ u16 Ks[128 * 64];
  __shared__ u16 Us[128 * 64];
  __shared__ u16 Ws[128 * 64];
  const int tid  = threadIdx.x;
  const int wave = tid >> 6;
  const int lane = tid & 63;
  const int quad = lane >> 4;
  const int tc   = lane & 15;
  const int bm = blockIdx.y * 128;
  const int bn = blockIdx.x * 128;
  const long long z = blockIdx.z;
  const long long sQ = (long long)S_LEN * D_MODEL;
  const int wm = (wave & 1) * 64;
  const int wn = (wave >> 1) * 64;

  f32x4 acc1[4][4], acc2[4][4];
#pragma unroll
  for (int i = 0; i < 4; i++)
#pragma unroll
    for (int j = 0; j < 4; j++) {
      acc1[i][j] = (f32x4){0.f, 0.f, 0.f, 0.f};
      acc2[i][j] = (f32x4){0.f, 0.f, 0.f, 0.f};
    }

  // staging lane geometry: one gl2lds = 1KB = 8 rows x 64 cols (u16)
  // LDS linear dest: row_local = chunk*8 + (lane>>3), c16 = lane&7
  // global source col16 pre-swizzled: c16_src = c16 ^ (row&7); row&7 == lane>>3
  const int srow8  = lane >> 3;                     // 0..7
  const int scol   = ((lane & 7) ^ srow8) * 8;      // swizzled col (u16 units)
  const int srowb  = wave * 32;                     // wave's 32-row stripe
  const u16* gq = Q  + z * sQ + (long long)(bm + srowb + srow8) * D_MODEL + scol;
  const u16* gk = Kt + z * sQ + (long long)(bn + srowb + srow8) * D_MODEL + scol;
  const u16* gu = Uq + z * sQ + (long long)(bm + srowb + srow8) * D_MODEL + scol;
  const u16* gw = Uk + z * sQ + (long long)(bn + srowb + srow8) * D_MODEL + scol;
  const int wb = srowb * 64;                        // u16 offset of wave stripe
  const long long r8 = 8LL * D_MODEL;               // 8 rows

  const int swzA = tc & 7;                          // row&7 for read swizzle

  for (int k0 = 0; k0 < D_MODEL; k0 += 64) {
#pragma unroll
    for (int c = 0; c < 4; c++) {
      gl2lds16(gq + c * r8, Qs + wb + c * 512);
      gl2lds16(gk + c * r8, Ks + wb + c * 512);
      gl2lds16(gu + c * r8, Us + wb + c * 512);
      gl2lds16(gw + c * r8, Ws + wb + c * 512);
    }
    gq += 64; gk += 64; gu += 64; gw += 64;
    __syncthreads();
    {   // GEMM 1: scores = Q @ K^T  (two k-slabs per tile)
      bf16x8 af[4][2], bg[4][2];
#pragma unroll
      for (int i = 0; i < 4; i++) {
        const int ra = (wm + i * 16 + tc) * 64;
        const int rb = (wn + i * 16 + tc) * 64;
#pragma unroll
        for (int ks = 0; ks < 2; ks++) {
          const int co = ((ks * 4 + quad) ^ swzA) * 8;
          af[i][ks] = *(const bf16x8*)(Qs + ra + co);
          bg[i][ks] = *(const bf16x8*)(Ks + rb + co);
        }
      }
#pragma unroll
      for (int i = 0; i < 4; i++)
#pragma unroll
        for (int j = 0; j < 4; j++) {
          acc1[i][j] = __builtin_amdgcn_mfma_f32_16x16x32_bf16(af[i][0], bg[j][0], acc1[i][j], 0, 0, 0);
          acc1[i][j] = __builtin_amdgcn_mfma_f32_16x16x32_bf16(af[i][1], bg[j][1], acc1[i][j], 0, 0, 0);
        }
    }
    {   // GEMM 2: sync = cos/sin phase product (Uq @ Uk^T)
      bf16x8 cf[4][2], dg[4][2];
#pragma unroll
      for (int i = 0; i < 4; i++) {
        const int ra = (wm + i * 16 + tc) * 64;
        const int rb = (wn + i * 16 + tc) * 64;
#pragma unroll
        for (int ks = 0; ks < 2; ks++) {
          const int co = ((ks * 4 + quad) ^ swzA) * 8;
          cf[i][ks] = *(const bf16x8*)(Us + ra + co);
          dg[i][ks] = *(const bf16x8*)(Ws + rb + co);
        }
      }
#pragma unroll
      for (int i = 0; i < 4; i++)
#pragma unroll
        for (int j = 0; j < 4; j++) {
          acc2[i][j] = __builtin_amdgcn_mfma_f32_16x16x32_bf16(cf[i][0], dg[j][0], acc2[i][j], 0, 0, 0);
          acc2[i][j] = __builtin_amdgcn_mfma_f32_16x16x32_bf16(cf[i][1], dg[j][1], acc2[i][j], 0, 0, 0);
        }
    }
    __syncthreads();
  }

  const float bif = *bifp;
  const float pc  = *pcp;
  float rsum[4][4], rsq[4][4];
#pragma unroll
  for (int i = 0; i < 4; i++)
#pragma unroll
    for (int r = 0; r < 4; r++) { rsum[i][r] = 0.f; rsq[i][r] = 0.f; }

  float* C = Cc + z * (long long)S_LEN * S_LEN;
#pragma unroll
  for (int i = 0; i < 4; i++) {
    const int row0 = bm + wm + i * 16 + quad * 4;
#pragma unroll
    for (int j = 0; j < 4; j++) {
      const int col = bn + wn + j * 16 + tc;
#pragma unroll
      for (int r = 0; r < 4; r++) {
        float sc = acc1[i][j][r] * 0.03125f;          // / sqrt(1024)
        float sy = acc2[i][j][r] * (1.0f / 512.0f);   // / HALF
        float t  = fast_tanh(sc);
        C[(long long)(row0 + r) * S_LEN + col] = sc + pc * sy + bif * t * (1.0f - t);
        rsum[i][r] += sy;
        rsq[i][r]  += sy * sy;
      }
    }
  }
#pragma unroll
  for (int m = 1; m < 16; m <<= 1) {
#pragma unroll
    for (int i = 0; i < 4; i++)
#pragma unroll
      for (int r = 0; r < 4; r++) {
        rsum[i][r] += __shfl_xor(rsum[i][r], m);
        rsq[i][r]  += __shfl_xor(rsq[i][r], m);
      }
  }
  if (tc == 0) {
#pragma unroll
    for (int i = 0; i < 4; i++)
#pragma unroll
      for (int r = 0; r < 4; r++) {
        long long rr = z * S_LEN + bm + wm + i * 16 + quad * 4 + r;
        atomicAdd(&ssum[rr], rsum[i][r]);
        atomicAdd(&ssq[rr],  rsq[i][r]);
      }
  }
}

// ============================================================
// Phase normalize in place on dense bf16 pf rows (stride 1024).
// Vectorized: bf16x8 loads/stores (16B/lane).
// ============================================================
__global__ __launch_bounds__(256)
void phase_norm_bf(u16* __restrict__ U, long long n_rows) {
  long long idx = (long long)blockIdx.x * 256 + threadIdx.x;
  if (idx >= n_rows * 64) return;          // 64 threads per row, 8 pairs each
  long long row = idx >> 6;
  int j0 = (int)(idx & 63) * 8;
  u16* p = U + row * D_MODEL + j0;
  bf16x8 re8 = *(const bf16x8*)p;
  bf16x8 im8 = *(const bf16x8*)(p + N_HALF);
  bf16x8 ro, io;
#pragma unroll
  for (int i = 0; i < 8; i++) {
    float re = bf2f((u16)re8[i]);
    float im = bf2f((u16)im8[i]);
    float n2 = re * re + im * im;
    float cr = 1.f, sr = 0.f;
    if (n2 > 0.f) {
      float inv = 1.0f / sqrtf(n2);
      cr = re * inv; sr = im * inv;
    }
    ro[i] = (short)f2bf(cr);
    io[i] = (short)f2bf(sr);
  }
  *(bf16x8*)p = ro;
  *(bf16x8*)(p + N_HALF) = io;
}

// ============================================================
// Row softmax: fp32 in (chaotic), bf16 out (attn). 1 block / row.
// ============================================================
__global__ __launch_bounds__(256)
void softmax_bf(const float* __restrict__ Cc, u16* __restrict__ P) {
  const long long row = (long long)blockIdx.y * S_LEN + blockIdx.x;
  const float* p = Cc + row * S_LEN;
  u16* q = P + row * S_LEN;
  const int tid = threadIdx.x;
  float v[8];
  float m = -3.402823466e+38f;
#pragma unroll
  for (int i = 0; i < 8; i++) { v[i] = p[tid + i * 256]; m = fmaxf(m, v[i]); }
#pragma unroll
  for (int mask = 1; mask < 64; mask <<= 1) m = fmaxf(m, __shfl_xor(m, mask));
  __shared__ float red[8];
  if ((tid & 63) == 0) red[tid >> 6] = m;
  __syncthreads();
  m = fmaxf(fmaxf(red[0], red[1]), fmaxf(red[2], red[3]));
  float s = 0.f;
#pragma unroll
  for (int i = 0; i < 8; i++) { v[i] = __expf(v[i] - m); s += v[i]; }
#pragma unroll
  for (int mask = 1; mask < 64; mask <<= 1) s += __shfl_xor(s, mask);
  __syncthreads();
  if ((tid & 63) == 0) red[4 + (tid >> 6)] = s;
  __syncthreads();
  s = red[4] + red[5] + red[6] + red[7];
  float inv = 1.0f / s;
#pragma unroll
  for (int i = 0; i < 8; i++) q[tid + i * 256] = f2bf(v[i] * inv);
}

// ============================================================
// sync_loss
// ============================================================
__global__ __launch_bounds__(1024)
void syncloss_kernel(const float* __restrict__ ssum, const float* __restrict__ ssq,
                     float* __restrict__ out) {
  const int tid = threadIdx.x;
  float acc = 0.f;
  for (int r = tid; r < N_BATCH * S_LEN; r += 1024) {
    float su = ssum[r], sq = ssq[r];
    acc += (sq - su * su * (1.0f / 2048.0f)) * (1.0f / 2047.0f);
  }
#pragma unroll
  for (int mask = 1; mask < 64; mask <<= 1) acc += __shfl_xor(acc, mask);
  __shared__ float red[16];
  if ((tid & 63) == 0) red[tid >> 6] = acc;
  __syncthreads();
  if (tid == 0) {
    float t = 0.f;
#pragma unroll
    for (int k = 0; k < 16; k++) t += red[k];
    out[0] = 0.01f * (t / (float)(N_BATCH * S_LEN));
  }
}

extern "C" void kernel_launch(void* const* d_in, const int* in_sizes, int n_in,
                              void* d_out, int out_size, void* d_ws, size_t ws_size,
                              hipStream_t stream) {
  const float* x    = (const float*)d_in[0];
  const float* Wq   = (const float*)d_in[1];
  const float* bq   = (const float*)d_in[2];
  const float* Wk   = (const float*)d_in[3];
  const float* bk   = (const float*)d_in[4];
  const float* Wv   = (const float*)d_in[5];
  const float* bv   = (const float*)d_in[6];
  const float* Wp   = (const float*)d_in[7];
  const float* bp   = (const float*)d_in[8];
  const float* Wo   = (const float*)d_in[9];
  const float* bo   = (const float*)d_in[10];
  const float* bifp = (const float*)d_in[11];
  const float* pcp  = (const float*)d_in[12];
  float* out = (float*)d_out;

  const long long NROW = (long long)N_BATCH * S_LEN;   // 8192
  const long long TD   = NROW * D_MODEL;               // 8,388,608
  const long long WSZ  = (long long)D_MODEL * D_MODEL; // 1,048,576

  // workspace layout (~171 MB)
  u16* xbf   = (u16*)d_ws;          // TD
  u16* wqb   = xbf + TD;            // WSZ
  u16* wkb   = wqb + WSZ;           // WSZ
  u16* wpb   = wkb + WSZ;           // WSZ
  u16* woh   = wpb + WSZ;           // WSZ (Wo hi/lo)
  u16* wol   = woh + WSZ;
  u16* wvth  = wol + WSZ;           // WSZ (Wv^T hi/lo)
  u16* wvtl  = wvth + WSZ;
  u16* w2h   = wvtl + WSZ;          // WSZ (W2 hi/lo)
  u16* w2l   = w2h + WSZ;
  float* W2f = (float*)(w2l + WSZ); // WSZ floats (4 MB)
  float* w2b = W2f + WSZ;           // 1024 floats
  u16* Qbf   = (u16*)(w2b + D_MODEL); // TD
  u16* Kbf   = Qbf + TD;            // TD (contiguous)
  u16* pfQ   = Kbf + TD;            // TD
  u16* pfK   = pfQ + TD;            // TD (contiguous)
  float* Cc  = (float*)(pfK + TD);  // B*S*S fp32 (67 MB)
  float* ssum = Cc + (long long)N_BATCH * S_LEN * S_LEN;
  float* ssq  = ssum + NROW;
  u16* attn = Qbf;                  // overlays Q+K after chaotic (2*TD)
  u16* vwh  = pfQ;                  // overlays Uq after chaotic
  u16* vwl  = pfK;                  // overlays Uk after chaotic

  dim3 blk(256);
  const long long sQ = (long long)S_LEN * D_MODEL;   // 2048*1024
  const long long sS = (long long)S_LEN * S_LEN;

  // ---- casts & W2 precompute ----
  cast_bf4<<<(int)(TD / 4 / 256), blk, 0, stream>>>(x, xbf, TD / 4);
  cast_bf4<<<(int)(WSZ / 4 / 256), blk, 0, stream>>>(Wq, wqb, WSZ / 4);
  cast_bf4<<<(int)(WSZ / 4 / 256), blk, 0, stream>>>(Wk, wkb, WSZ / 4);
  cast_bf4<<<(int)(WSZ / 4 / 256), blk, 0, stream>>>(Wp, wpb, WSZ / 4);
  cast_split<<<(int)(WSZ / 256), blk, 0, stream>>>(Wo, woh, wol, WSZ);
  transpose_split<<<dim3(32, 32), blk, 0, stream>>>(Wv, wvth, wvtl);
  // W2 = split(Wo) @ split(Wv^T)^T  (fp32), then split; w2b = Wo @ bv
  mfma_gemm_out3<<<dim3(8, 8, 1), blk, 0, stream>>>(
      woh, wol, wvth, wvtl, nullptr, W2f, D_MODEL, D_MODEL);
  cast_split<<<(int)(WSZ / 256), blk, 0, stream>>>(W2f, w2h, w2l, WSZ);
  w2_bias<<<D_MODEL, blk, 0, stream>>>(Wo, bv, w2b);

  // ---- Q,K fused projection ----
  qk_fused<<<dim3(8, 64), blk, 0, stream>>>(xbf, wqb, wkb, bq, bk, Qbf, Kbf);
  // ---- pfQ,pfK fused projection ----
  pf_fused<<<dim3(8, 64), blk, 0, stream>>>(Qbf, wpb, bp, pfQ, pfK, TD);
  phase_norm_bf<<<(int)(2 * NROW * 64 / 256), blk, 0, stream>>>(pfQ, 2 * NROW);
  zero_stats<<<(int)((2 * NROW + 255) / 256), blk, 0, stream>>>(ssum, (int)(2 * NROW));

  // ---- fused scores + sync + chaotic ----
  chaotic_fused<<<dim3(16, 16, N_BATCH), blk, 0, stream>>>(
      Qbf, Kbf, pfQ, pfK, Cc, ssum, ssq, bifp, pcp);
  // ---- VWt = split(W2) @ x_b^T + w2b (overlays pf, dead after chaotic) ----
  vwt_kernel<<<dim3(16, 8, N_BATCH), blk, 0, stream>>>(
      w2h, w2l, xbf, w2b, vwh, vwl, sQ, sQ);
  // ---- softmax (overlays Q/K) ----
  softmax_bf<<<dim3(S_LEN, N_BATCH), blk, 0, stream>>>(Cc, attn);
  // ---- out = attn @ (VWth+VWtl)^T + bo ----
  gemm_bsplit<<<dim3(8, 16, N_BATCH), blk, 0, stream>>>(
      attn, vwh, vwl, bo, out,
      D_MODEL, S_LEN, sS, sQ, sQ);
  // ---- sync_loss ----
  syncloss_kernel<<<1, 1024, 0, stream>>>(ssum, ssq, out + TD);
}

// Round 3
// 488.288 us; speedup vs baseline: 1.1569x; 1.0390x over previous
//
#include <hip/hip_runtime.h>
#include <hip/hip_bf16.h>
#include <math.h>

#define S_LEN 2048
#define D_MODEL 1024
#define N_BATCH 4
#define N_HALF 512

typedef unsigned short u16;
typedef __attribute__((ext_vector_type(8))) short bf16x8;
typedef __attribute__((ext_vector_type(4))) float f32x4;

// ---------- helpers ----------
__device__ inline u16 f2bf(float v) {
  __hip_bfloat16 h = __float2bfloat16(v);   // RNE
  return *reinterpret_cast<u16*>(&h);
}
__device__ inline float bf2f(u16 u) {
  __hip_bfloat16 h = *reinterpret_cast<__hip_bfloat16*>(&u);
  return __bfloat162float(h);
}
// async global->LDS, 16B per lane; LDS dest is wave-uniform base + lane*16
__device__ inline void gl2lds16(const void* g, void* l) {
  __builtin_amdgcn_global_load_lds(
      (const __attribute__((address_space(1))) unsigned int*)g,
      (__attribute__((address_space(3))) unsigned int*)l, 16, 0, 0);
}
// tanh via v_exp_f32; exact at 0, saturates correctly at +/-inf (no NaN)
__device__ inline float fast_tanh(float x) {
  float e = __expf(2.0f * x);
  return 1.0f - 2.0f / (e + 1.0f);
}

// ---------- casts ----------
__global__ __launch_bounds__(256)
void cast_bf4(const float* __restrict__ src, u16* __restrict__ dst, long long n4) {
  long long i = (long long)blockIdx.x * 256 + threadIdx.x;
  if (i >= n4) return;
  float4 v = ((const float4*)src)[i];
  ushort4 o;
  o.x = f2bf(v.x); o.y = f2bf(v.y); o.z = f2bf(v.z); o.w = f2bf(v.w);
  ((ushort4*)dst)[i] = o;
}
__global__ __launch_bounds__(256)
void cast_split(const float* __restrict__ src, u16* __restrict__ hi,
                u16* __restrict__ lo, long long n) {
  long long i = (long long)blockIdx.x * 256 + threadIdx.x;
  if (i < n) {
    float v = src[i];
    u16 h = f2bf(v);
    hi[i] = h;
    lo[i] = f2bf(v - bf2f(h));
  }
}
// transpose + split: dst[i][j] = split(src[j][i]), 1024x1024
__global__ __launch_bounds__(256)
void transpose_split(const float* __restrict__ src, u16* __restrict__ hi,
                     u16* __restrict__ lo) {
  __shared__ float t[32][33];
  const int bx = blockIdx.x * 32;   // i-base (src col, dst row)
  const int by = blockIdx.y * 32;   // j-base (src row, dst col)
  const int c = threadIdx.x & 31;
  const int r0 = (threadIdx.x >> 5) * 4;
#pragma unroll
  for (int r = 0; r < 4; r++)
    t[r0 + r][c] = src[(long long)(by + r0 + r) * D_MODEL + bx + c];
  __syncthreads();
#pragma unroll
  for (int r = 0; r < 4; r++) {
    float v = t[c][r0 + r];
    long long idx = (long long)(bx + r0 + r) * D_MODEL + by + c;
    u16 h = f2bf(v);
    hi[idx] = h;
    lo[idx] = f2bf(v - bf2f(h));
  }
}
__global__ __launch_bounds__(256)
void zero_stats(float* __restrict__ p, int n) {
  int i = blockIdx.x * 256 + threadIdx.x;
  if (i < n) p[i] = 0.f;
}
// w2b[d] = sum_j Wo[d][j] * bv[j]   (one block per d)
__global__ __launch_bounds__(256)
void w2_bias(const float* __restrict__ Wo, const float* __restrict__ bv,
             float* __restrict__ w2b) {
  const int d = blockIdx.x;
  const int tid = threadIdx.x;
  float acc = 0.f;
  for (int j = tid; j < D_MODEL; j += 256)
    acc += Wo[(long long)d * D_MODEL + j] * bv[j];
#pragma unroll
  for (int m = 1; m < 64; m <<= 1) acc += __shfl_xor(acc, m);
  __shared__ float red[4];
  if ((tid & 63) == 0) red[tid >> 6] = acc;
  __syncthreads();
  if (tid == 0) w2b[d] = red[0] + red[1] + red[2] + red[3];
}

// ============================================================
// Staging/read geometry shared by all BK=64 swizzled GEMMs
// (validated on chaotic_fused round 2: conflicts 8.4M -> 0):
//   one gl2lds = 1KB = 8 rows x 64 u16; lane l -> LDS row l>>3, c16blk l&7.
//   global source col16 pre-swizzled: c16blk_src = (l&7) ^ (l>>3).
//   read of k-block kblk at row rr comes from LDS col block kblk ^ (rr&7);
//   rr&7 == tc&7 for all fragment rows (wm/wn, i*16 are mult of 8).
// ============================================================

// ============================================================
// Fused Q+K projection: dual-acc NT GEMM sharing the A (=x) staging.
// BK=64 + XOR swizzle, 48 KB LDS, 2 blocks/CU.
// ============================================================
__global__ __launch_bounds__(256, 2)
void qk_fused(const u16* __restrict__ X, const u16* __restrict__ Wq,
              const u16* __restrict__ Wk,
              const float* __restrict__ bq, const float* __restrict__ bk,
              u16* __restrict__ Qo, u16* __restrict__ Ko) {
  __shared__ u16 Xs[128 * 64];
  __shared__ u16 Qs[128 * 64];
  __shared__ u16 Ks[128 * 64];
  const int tid  = threadIdx.x;
  const int wave = tid >> 6;
  const int lane = tid & 63;
  const int quad = lane >> 4;
  const int tc   = lane & 15;
  const int bm = blockIdx.y * 128;
  const int bn = blockIdx.x * 128;
  const int wm = (wave & 1) * 64;
  const int wn = (wave >> 1) * 64;

  f32x4 acc1[4][4], acc2[4][4];
#pragma unroll
  for (int i = 0; i < 4; i++)
#pragma unroll
    for (int j = 0; j < 4; j++) {
      acc1[i][j] = (f32x4){0.f, 0.f, 0.f, 0.f};
      acc2[i][j] = (f32x4){0.f, 0.f, 0.f, 0.f};
    }

  const int srow8 = lane >> 3;
  const int scol  = ((lane & 7) ^ srow8) * 8;
  const int srowb = wave * 32;
  const u16* gx = X  + (long long)(bm + srowb + srow8) * D_MODEL + scol;
  const u16* gq = Wq + (long long)(bn + srowb + srow8) * D_MODEL + scol;
  const u16* gk = Wk + (long long)(bn + srowb + srow8) * D_MODEL + scol;
  const int wb = srowb * 64;
  const long long r8 = 8LL * D_MODEL;
  const int swzA = tc & 7;

  for (int k0 = 0; k0 < D_MODEL; k0 += 64) {
#pragma unroll
    for (int c = 0; c < 4; c++) {
      gl2lds16(gx + c * r8, Xs + wb + c * 512);
      gl2lds16(gq + c * r8, Qs + wb + c * 512);
      gl2lds16(gk + c * r8, Ks + wb + c * 512);
    }
    gx += 64; gq += 64; gk += 64;
    __syncthreads();
    bf16x8 af[4][2], bq4[4][2], bk4[4][2];
#pragma unroll
    for (int i = 0; i < 4; i++) {
      const int ra = (wm + i * 16 + tc) * 64;
      const int rb = (wn + i * 16 + tc) * 64;
#pragma unroll
      for (int ks = 0; ks < 2; ks++) {
        const int co = ((ks * 4 + quad) ^ swzA) * 8;
        af[i][ks]  = *(const bf16x8*)(Xs + ra + co);
        bq4[i][ks] = *(const bf16x8*)(Qs + rb + co);
        bk4[i][ks] = *(const bf16x8*)(Ks + rb + co);
      }
    }
#pragma unroll
    for (int i = 0; i < 4; i++)
#pragma unroll
      for (int j = 0; j < 4; j++) {
        acc1[i][j] = __builtin_amdgcn_mfma_f32_16x16x32_bf16(af[i][0], bq4[j][0], acc1[i][j], 0, 0, 0);
        acc2[i][j] = __builtin_amdgcn_mfma_f32_16x16x32_bf16(af[i][0], bk4[j][0], acc2[i][j], 0, 0, 0);
        acc1[i][j] = __builtin_amdgcn_mfma_f32_16x16x32_bf16(af[i][1], bq4[j][1], acc1[i][j], 0, 0, 0);
        acc2[i][j] = __builtin_amdgcn_mfma_f32_16x16x32_bf16(af[i][1], bk4[j][1], acc2[i][j], 0, 0, 0);
      }
    __syncthreads();
  }

#pragma unroll
  for (int i = 0; i < 4; i++) {
    const int row0 = bm + wm + i * 16 + quad * 4;
#pragma unroll
    for (int j = 0; j < 4; j++) {
      const int col = bn + wn + j * 16 + tc;
#pragma unroll
      for (int r = 0; r < 4; r++) {
        long long idx = (long long)(row0 + r) * D_MODEL + col;
        Qo[idx] = f2bf(acc1[i][j][r] + bq[col]);
        Ko[idx] = f2bf(acc2[i][j][r] + bk[col]);
      }
    }
  }
}

// ============================================================
// Fused pfQ+pfK projection: dual-acc NT GEMM sharing the B (=Wp) staging.
// BK=64 + XOR swizzle, 48 KB LDS, 2 blocks/CU.
// ============================================================
__global__ __launch_bounds__(256, 2)
void pf_fused(const u16* __restrict__ Qb, const u16* __restrict__ Wp,
              const float* __restrict__ bp,
              u16* __restrict__ pfQ, u16* __restrict__ pfK,
              long long TDo) {
  __shared__ u16 Qs[128 * 64];
  __shared__ u16 Ks[128 * 64];
  __shared__ u16 Ws[128 * 64];
  const int tid  = threadIdx.x;
  const int wave = tid >> 6;
  const int lane = tid & 63;
  const int quad = lane >> 4;
  const int tc   = lane & 15;
  const int bm = blockIdx.y * 128;
  const int bn = blockIdx.x * 128;
  const int wm = (wave & 1) * 64;
  const int wn = (wave >> 1) * 64;

  f32x4 acc1[4][4], acc2[4][4];
#pragma unroll
  for (int i = 0; i < 4; i++)
#pragma unroll
    for (int j = 0; j < 4; j++) {
      acc1[i][j] = (f32x4){0.f, 0.f, 0.f, 0.f};
      acc2[i][j] = (f32x4){0.f, 0.f, 0.f, 0.f};
    }

  const int srow8 = lane >> 3;
  const int scol  = ((lane & 7) ^ srow8) * 8;
  const int srowb = wave * 32;
  const u16* gq = Qb + (long long)(bm + srowb + srow8) * D_MODEL + scol;
  const u16* gk = gq + TDo;
  const u16* gw = Wp + (long long)(bn + srowb + srow8) * D_MODEL + scol;
  const int wb = srowb * 64;
  const long long r8 = 8LL * D_MODEL;
  const int swzA = tc & 7;

  for (int k0 = 0; k0 < D_MODEL; k0 += 64) {
#pragma unroll
    for (int c = 0; c < 4; c++) {
      gl2lds16(gq + c * r8, Qs + wb + c * 512);
      gl2lds16(gk + c * r8, Ks + wb + c * 512);
      gl2lds16(gw + c * r8, Ws + wb + c * 512);
    }
    gq += 64; gk += 64; gw += 64;
    __syncthreads();
    bf16x8 aq[4][2], ak[4][2], bw[4][2];
#pragma unroll
    for (int i = 0; i < 4; i++) {
      const int ra = (wm + i * 16 + tc) * 64;
      const int rb = (wn + i * 16 + tc) * 64;
#pragma unroll
      for (int ks = 0; ks < 2; ks++) {
        const int co = ((ks * 4 + quad) ^ swzA) * 8;
        aq[i][ks] = *(const bf16x8*)(Qs + ra + co);
        ak[i][ks] = *(const bf16x8*)(Ks + ra + co);
        bw[i][ks] = *(const bf16x8*)(Ws + rb + co);
      }
    }
#pragma unroll
    for (int i = 0; i < 4; i++)
#pragma unroll
      for (int j = 0; j < 4; j++) {
        acc1[i][j] = __builtin_amdgcn_mfma_f32_16x16x32_bf16(aq[i][0], bw[j][0], acc1[i][j], 0, 0, 0);
        acc2[i][j] = __builtin_amdgcn_mfma_f32_16x16x32_bf16(ak[i][0], bw[j][0], acc2[i][j], 0, 0, 0);
        acc1[i][j] = __builtin_amdgcn_mfma_f32_16x16x32_bf16(aq[i][1], bw[j][1], acc1[i][j], 0, 0, 0);
        acc2[i][j] = __builtin_amdgcn_mfma_f32_16x16x32_bf16(ak[i][1], bw[j][1], acc2[i][j], 0, 0, 0);
      }
    __syncthreads();
  }

#pragma unroll
  for (int i = 0; i < 4; i++) {
    const int row0 = bm + wm + i * 16 + quad * 4;
#pragma unroll
    for (int j = 0; j < 4; j++) {
      const int col = bn + wn + j * 16 + tc;
#pragma unroll
      for (int r = 0; r < 4; r++) {
        long long idx = (long long)(row0 + r) * D_MODEL + col;
        float b = bp[col];
        pfQ[idx] = f2bf(acc1[i][j][r] + b);
        pfK[idx] = f2bf(acc2[i][j][r] + b);
      }
    }
  }
}

// ============================================================
// Split-precision GEMM: C = (Ah+Al)(Bh+Bl)^T (+bias), fp32 out.
// 3 MFMAs per frag step. BK=64 + XOR swizzle, 64 KB LDS.
// ============================================================
__global__ __launch_bounds__(256)
void mfma_gemm_out3(const u16* __restrict__ Ah, const u16* __restrict__ Al,
                    const u16* __restrict__ Bh, const u16* __restrict__ Bl,
                    const float* __restrict__ bias, float* __restrict__ C,
                    int N, int K) {
  __shared__ u16 Ash[128 * 64];
  __shared__ u16 Asl[128 * 64];
  __shared__ u16 Bsh[128 * 64];
  __shared__ u16 Bsl[128 * 64];
  const int tid  = threadIdx.x;
  const int wave = tid >> 6;
  const int lane = tid & 63;
  const int quad = lane >> 4;
  const int tc   = lane & 15;
  const int bm = blockIdx.y * 128;
  const int bn = blockIdx.x * 128;
  const int wm = (wave & 1) * 64;
  const int wn = (wave >> 1) * 64;

  f32x4 acc[4][4];
#pragma unroll
  for (int i = 0; i < 4; i++)
#pragma unroll
    for (int j = 0; j < 4; j++) acc[i][j] = (f32x4){0.f, 0.f, 0.f, 0.f};

  const int srow8 = lane >> 3;
  const int scol  = ((lane & 7) ^ srow8) * 8;
  const int srowb = wave * 32;
  long long aoff = (long long)(bm + srowb + srow8) * K + scol;
  long long boff = (long long)(bn + srowb + srow8) * K + scol;
  const u16 *gah = Ah + aoff, *gal = Al + aoff;
  const u16 *gbh = Bh + boff, *gbl = Bl + boff;
  const int wb = srowb * 64;
  const long long r8K = 8LL * K;
  const int swzA = tc & 7;

  for (int k0 = 0; k0 < K; k0 += 64) {
#pragma unroll
    for (int c = 0; c < 4; c++) {
      gl2lds16(gah + c * r8K, Ash + wb + c * 512);
      gl2lds16(gal + c * r8K, Asl + wb + c * 512);
      gl2lds16(gbh + c * r8K, Bsh + wb + c * 512);
      gl2lds16(gbl + c * r8K, Bsl + wb + c * 512);
    }
    gah += 64; gal += 64; gbh += 64; gbl += 64;
    __syncthreads();
    bf16x8 ah[4][2], al[4][2], bh[4][2], bl[4][2];
#pragma unroll
    for (int i = 0; i < 4; i++) {
      const int ra = (wm + i * 16 + tc) * 64;
      const int rb = (wn + i * 16 + tc) * 64;
#pragma unroll
      for (int ks = 0; ks < 2; ks++) {
        const int co = ((ks * 4 + quad) ^ swzA) * 8;
        ah[i][ks] = *(const bf16x8*)(Ash + ra + co);
        al[i][ks] = *(const bf16x8*)(Asl + ra + co);
        bh[i][ks] = *(const bf16x8*)(Bsh + rb + co);
        bl[i][ks] = *(const bf16x8*)(Bsl + rb + co);
      }
    }
#pragma unroll
    for (int i = 0; i < 4; i++)
#pragma unroll
      for (int j = 0; j < 4; j++) {
#pragma unroll
        for (int ks = 0; ks < 2; ks++) {
          acc[i][j] = __builtin_amdgcn_mfma_f32_16x16x32_bf16(ah[i][ks], bh[j][ks], acc[i][j], 0, 0, 0);
          acc[i][j] = __builtin_amdgcn_mfma_f32_16x16x32_bf16(ah[i][ks], bl[j][ks], acc[i][j], 0, 0, 0);
          acc[i][j] = __builtin_amdgcn_mfma_f32_16x16x32_bf16(al[i][ks], bh[j][ks], acc[i][j], 0, 0, 0);
        }
      }
    __syncthreads();
  }
#pragma unroll
  for (int i = 0; i < 4; i++) {
    const int row0 = bm + wm + i * 16 + quad * 4;
#pragma unroll
    for (int j = 0; j < 4; j++) {
      const int col = bn + wn + j * 16 + tc;
      float b = bias ? bias[col] : 0.f;
#pragma unroll
      for (int r = 0; r < 4; r++)
        C[(long long)(row0 + r) * N + col] = acc[i][j][r] + b;
    }
  }
}

// ============================================================
// VWt[b][d][s] = (W2h+W2l) @ x_b^T + w2b[d], hi/lo bf16 out.
// BK=64 + XOR swizzle, 48 KB LDS.
// ============================================================
__global__ __launch_bounds__(256)
void vwt_kernel(const u16* __restrict__ W2h, const u16* __restrict__ W2l,
                const u16* __restrict__ X, const float* __restrict__ w2b,
                u16* __restrict__ Ch, u16* __restrict__ Cl,
                long long sB, long long sC) {
  __shared__ u16 Ah[128 * 64];
  __shared__ u16 Al[128 * 64];
  __shared__ u16 Bs[128 * 64];
  const int tid  = threadIdx.x;
  const int wave = tid >> 6;
  const int lane = tid & 63;
  const int quad = lane >> 4;
  const int tc   = lane & 15;
  const int bm = blockIdx.y * 128;   // d
  const int bn = blockIdx.x * 128;   // s
  const long long z = blockIdx.z;
  const int wm = (wave & 1) * 64;
  const int wn = (wave >> 1) * 64;

  f32x4 acc[4][4];
#pragma unroll
  for (int i = 0; i < 4; i++)
#pragma unroll
    for (int j = 0; j < 4; j++) acc[i][j] = (f32x4){0.f, 0.f, 0.f, 0.f};

  const int srow8 = lane >> 3;
  const int scol  = ((lane & 7) ^ srow8) * 8;
  const int srowb = wave * 32;
  const long long aoff = (long long)(bm + srowb + srow8) * D_MODEL + scol;
  const u16* gah = W2h + aoff;
  const u16* gal = W2l + aoff;
  const u16* gb  = X + z * sB + (long long)(bn + srowb + srow8) * D_MODEL + scol;
  const int wb = srowb * 64;
  const long long r8 = 8LL * D_MODEL;
  const int swzA = tc & 7;

  for (int k0 = 0; k0 < D_MODEL; k0 += 64) {
#pragma unroll
    for (int c = 0; c < 4; c++) {
      gl2lds16(gah + c * r8, Ah + wb + c * 512);
      gl2lds16(gal + c * r8, Al + wb + c * 512);
      gl2lds16(gb  + c * r8, Bs + wb + c * 512);
    }
    gah += 64; gal += 64; gb += 64;
    __syncthreads();
    bf16x8 ah4[4][2], al4[4][2], bx[4][2];
#pragma unroll
    for (int i = 0; i < 4; i++) {
      const int ra = (wm + i * 16 + tc) * 64;
      const int rb = (wn + i * 16 + tc) * 64;
#pragma unroll
      for (int ks = 0; ks < 2; ks++) {
        const int co = ((ks * 4 + quad) ^ swzA) * 8;
        ah4[i][ks] = *(const bf16x8*)(Ah + ra + co);
        al4[i][ks] = *(const bf16x8*)(Al + ra + co);
        bx[i][ks]  = *(const bf16x8*)(Bs + rb + co);
      }
    }
#pragma unroll
    for (int i = 0; i < 4; i++)
#pragma unroll
      for (int j = 0; j < 4; j++) {
        acc[i][j] = __builtin_amdgcn_mfma_f32_16x16x32_bf16(ah4[i][0], bx[j][0], acc[i][j], 0, 0, 0);
        acc[i][j] = __builtin_amdgcn_mfma_f32_16x16x32_bf16(al4[i][0], bx[j][0], acc[i][j], 0, 0, 0);
        acc[i][j] = __builtin_amdgcn_mfma_f32_16x16x32_bf16(ah4[i][1], bx[j][1], acc[i][j], 0, 0, 0);
        acc[i][j] = __builtin_amdgcn_mfma_f32_16x16x32_bf16(al4[i][1], bx[j][1], acc[i][j], 0, 0, 0);
      }
    __syncthreads();
  }

  u16* Chz = Ch + z * sC;
  u16* Clz = Cl + z * sC;
#pragma unroll
  for (int i = 0; i < 4; i++) {
    const int row0 = bm + wm + i * 16 + quad * 4;
#pragma unroll
    for (int j = 0; j < 4; j++) {
      const int col = bn + wn + j * 16 + tc;
#pragma unroll
      for (int r = 0; r < 4; r++) {
        float v = acc[i][j][r] + w2b[row0 + r];
        long long idx = (long long)(row0 + r) * S_LEN + col;
        u16 h = f2bf(v);
        Chz[idx] = h;
        Clz[idx] = f2bf(v - bf2f(h));
      }
    }
  }
}

// ============================================================
// B-split GEMM (out): C = A @ (Bh+Bl)^T + bias[col], fp32 out.
// BK=64 + XOR swizzle, 48 KB LDS.
// ============================================================
__global__ __launch_bounds__(256)
void gemm_bsplit(const u16* __restrict__ A,
                 const u16* __restrict__ Bh, const u16* __restrict__ Bl,
                 const float* __restrict__ bias, float* __restrict__ C,
                 int N, int K, long long sA, long long sB, long long sC) {
  __shared__ u16 As[128 * 64];
  __shared__ u16 Bsh[128 * 64];
  __shared__ u16 Bsl[128 * 64];
  const int tid  = threadIdx.x;
  const int wave = tid >> 6;
  const int lane = tid & 63;
  const int quad = lane >> 4;
  const int tc   = lane & 15;
  const int bm = blockIdx.y * 128;
  const int bn = blockIdx.x * 128;
  const long long z = blockIdx.z;
  const int wm = (wave & 1) * 64;
  const int wn = (wave >> 1) * 64;

  f32x4 acc[4][4];
#pragma unroll
  for (int i = 0; i < 4; i++)
#pragma unroll
    for (int j = 0; j < 4; j++) acc[i][j] = (f32x4){0.f, 0.f, 0.f, 0.f};

  const int srow8 = lane >> 3;
  const int scol  = ((lane & 7) ^ srow8) * 8;
  const int srowb = wave * 32;
  const long long boff = (long long)(bn + srowb + srow8) * K + scol;
  const u16* ga  = A + z * sA + (long long)(bm + srowb + srow8) * K + scol;
  const u16* gbh = Bh + z * sB + boff;
  const u16* gbl = Bl + z * sB + boff;
  const int wb = srowb * 64;
  const long long r8K = 8LL * K;
  const int swzA = tc & 7;

  for (int k0 = 0; k0 < K; k0 += 64) {
#pragma unroll
    for (int c = 0; c < 4; c++) {
      gl2lds16(ga  + c * r8K, As  + wb + c * 512);
      gl2lds16(gbh + c * r8K, Bsh + wb + c * 512);
      gl2lds16(gbl + c * r8K, Bsl + wb + c * 512);
    }
    ga += 64; gbh += 64; gbl += 64;
    __syncthreads();
    bf16x8 af[4][2], bh[4][2], bl[4][2];
#pragma unroll
    for (int i = 0; i < 4; i++) {
      const int ra = (wm + i * 16 + tc) * 64;
      const int rb = (wn + i * 16 + tc) * 64;
#pragma unroll
      for (int ks = 0; ks < 2; ks++) {
        const int co = ((ks * 4 + quad) ^ swzA) * 8;
        af[i][ks] = *(const bf16x8*)(As  + ra + co);
        bh[i][ks] = *(const bf16x8*)(Bsh + rb + co);
        bl[i][ks] = *(const bf16x8*)(Bsl + rb + co);
      }
    }
#pragma unroll
    for (int i = 0; i < 4; i++)
#pragma unroll
      for (int j = 0; j < 4; j++) {
        acc[i][j] = __builtin_amdgcn_mfma_f32_16x16x32_bf16(af[i][0], bh[j][0], acc[i][j], 0, 0, 0);
        acc[i][j] = __builtin_amdgcn_mfma_f32_16x16x32_bf16(af[i][0], bl[j][0], acc[i][j], 0, 0, 0);
        acc[i][j] = __builtin_amdgcn_mfma_f32_16x16x32_bf16(af[i][1], bh[j][1], acc[i][j], 0, 0, 0);
        acc[i][j] = __builtin_amdgcn_mfma_f32_16x16x32_bf16(af[i][1], bl[j][1], acc[i][j], 0, 0, 0);
      }
    __syncthreads();
  }

  float* Cz = C + z * sC;
#pragma unroll
  for (int i = 0; i < 4; i++) {
    const int row0 = bm + wm + i * 16 + quad * 4;
#pragma unroll
    for (int j = 0; j < 4; j++) {
      const int col = bn + wn + j * 16 + tc;
#pragma unroll
      for (int r = 0; r < 4; r++)
        Cz[(long long)(row0 + r) * N + col] = acc[i][j][r] + bias[col];
    }
  }
}

// ============================================================
// Fused chaotic kernel — BK=64 + XOR-swizzled LDS (round-2 validated body).
// ============================================================
__global__ __launch_bounds__(256, 2)
void chaotic_fused(const u16* __restrict__ Q, const u16* __restrict__ Kt,
                   const u16* __restrict__ Uq, const u16* __restrict__ Uk,
                   float* __restrict__ Cc,
                   float* __restrict__ ssum, float* __restrict__ ssq,
                   const float* __restrict__ bifp, const float* __restrict__ pcp) {
  __shared__ u16 Qs[128 * 64];
  __shared__ u16 Ks[128 * 64];
  __shared__ u16 Us[128 * 64];
  __shared__ u16 Ws[128 * 64];
  const int tid  = threadIdx.x;
  const int wave = tid >> 6;
  const int lane = tid & 63;
  const int quad = lane >> 4;
  const int tc   = lane & 15;
  const int bm = blockIdx.y * 128;
  const int bn = blockIdx.x * 128;
  const long long z = blockIdx.z;
  const long long sQ = (long long)S_LEN * D_MODEL;
  const int wm = (wave & 1) * 64;
  const int wn = (wave >> 1) * 64;

  f32x4 acc1[4][4], acc2[4][4];
#pragma unroll
  for (int i = 0; i < 4; i++)
#pragma unroll
    for (int j = 0; j < 4; j++) {
      acc1[i][j] = (f32x4){0.f, 0.f, 0.f, 0.f};
      acc2[i][j] = (f32x4){0.f, 0.f, 0.f, 0.f};
    }

  const int srow8  = lane >> 3;                     // 0..7
  const int scol   = ((lane & 7) ^ srow8) * 8;      // swizzled col (u16 units)
  const int srowb  = wave * 32;                     // wave's 32-row stripe
  const u16* gq = Q  + z * sQ + (long long)(bm + srowb + srow8) * D_MODEL + scol;
  const u16* gk = Kt + z * sQ + (long long)(bn + srowb + srow8) * D_MODEL + scol;
  const u16* gu = Uq + z * sQ + (long long)(bm + srowb + srow8) * D_MODEL + scol;
  const u16* gw = Uk + z * sQ + (long long)(bn + srowb + srow8) * D_MODEL + scol;
  const int wb = srowb * 64;                        // u16 offset of wave stripe
  const long long r8 = 8LL * D_MODEL;               // 8 rows

  const int swzA = tc & 7;                          // row&7 for read swizzle

  for (int k0 = 0; k0 < D_MODEL; k0 += 64) {
#pragma unroll
    for (int c = 0; c < 4; c++) {
      gl2lds16(gq + c * r8, Qs + wb + c * 512);
      gl2lds16(gk + c * r8, Ks + wb + c * 512);
      gl2lds16(gu + c * r8, Us + wb + c * 512);
      gl2lds16(gw + c * r8, Ws + wb + c * 512);
    }
    gq += 64; gk += 64; gu += 64; gw += 64;
    __syncthreads();
    {   // GEMM 1: scores = Q @ K^T  (two k-slabs per tile)
      bf16x8 af[4][2], bg[4][2];
#pragma unroll
      for (int i = 0; i < 4; i++) {
        const int ra = (wm + i * 16 + tc) * 64;
        const int rb = (wn + i * 16 + tc) * 64;
#pragma unroll
        for (int ks = 0; ks < 2; ks++) {
          const int co = ((ks * 4 + quad) ^ swzA) * 8;
          af[i][ks] = *(const bf16x8*)(Qs + ra + co);
          bg[i][ks] = *(const bf16x8*)(Ks + rb + co);
        }
      }
#pragma unroll
      for (int i = 0; i < 4; i++)
#pragma unroll
        for (int j = 0; j < 4; j++) {
          acc1[i][j] = __builtin_amdgcn_mfma_f32_16x16x32_bf16(af[i][0], bg[j][0], acc1[i][j], 0, 0, 0);
          acc1[i][j] = __builtin_amdgcn_mfma_f32_16x16x32_bf16(af[i][1], bg[j][1], acc1[i][j], 0, 0, 0);
        }
    }
    {   // GEMM 2: sync = cos/sin phase product (Uq @ Uk^T)
      bf16x8 cf[4][2], dg[4][2];
#pragma unroll
      for (int i = 0; i < 4; i++) {
        const int ra = (wm + i * 16 + tc) * 64;
        const int rb = (wn + i * 16 + tc) * 64;
#pragma unroll
        for (int ks = 0; ks < 2; ks++) {
          const int co = ((ks * 4 + quad) ^ swzA) * 8;
          cf[i][ks] = *(const bf16x8*)(Us + ra + co);
          dg[i][ks] = *(const bf16x8*)(Ws + rb + co);
        }
      }
#pragma unroll
      for (int i = 0; i < 4; i++)
#pragma unroll
        for (int j = 0; j < 4; j++) {
          acc2[i][j] = __builtin_amdgcn_mfma_f32_16x16x32_bf16(cf[i][0], dg[j][0], acc2[i][j], 0, 0, 0);
          acc2[i][j] = __builtin_amdgcn_mfma_f32_16x16x32_bf16(cf[i][1], dg[j][1], acc2[i][j], 0, 0, 0);
        }
    }
    __syncthreads();
  }

  const float bif = *bifp;
  const float pc  = *pcp;
  float rsum[4][4], rsq[4][4];
#pragma unroll
  for (int i = 0; i < 4; i++)
#pragma unroll
    for (int r = 0; r < 4; r++) { rsum[i][r] = 0.f; rsq[i][r] = 0.f; }

  float* C = Cc + z * (long long)S_LEN * S_LEN;
#pragma unroll
  for (int i = 0; i < 4; i++) {
    const int row0 = bm + wm + i * 16 + quad * 4;
#pragma unroll
    for (int j = 0; j < 4; j++) {
      const int col = bn + wn + j * 16 + tc;
#pragma unroll
      for (int r = 0; r < 4; r++) {
        float sc = acc1[i][j][r] * 0.03125f;          // / sqrt(1024)
        float sy = acc2[i][j][r] * (1.0f / 512.0f);   // / HALF
        float t  = fast_tanh(sc);
        C[(long long)(row0 + r) * S_LEN + col] = sc + pc * sy + bif * t * (1.0f - t);
        rsum[i][r] += sy;
        rsq[i][r]  += sy * sy;
      }
    }
  }
#pragma unroll
  for (int m = 1; m < 16; m <<= 1) {
#pragma unroll
    for (int i = 0; i < 4; i++)
#pragma unroll
      for (int r = 0; r < 4; r++) {
        rsum[i][r] += __shfl_xor(rsum[i][r], m);
        rsq[i][r]  += __shfl_xor(rsq[i][r], m);
      }
  }
  if (tc == 0) {
#pragma unroll
    for (int i = 0; i < 4; i++)
#pragma unroll
      for (int r = 0; r < 4; r++) {
        long long rr = z * S_LEN + bm + wm + i * 16 + quad * 4 + r;
        atomicAdd(&ssum[rr], rsum[i][r]);
        atomicAdd(&ssq[rr],  rsq[i][r]);
      }
  }
}

// ============================================================
// Phase normalize in place on dense bf16 pf rows (stride 1024).
// Vectorized: bf16x8 loads/stores (16B/lane).
// ============================================================
__global__ __launch_bounds__(256)
void phase_norm_bf(u16* __restrict__ U, long long n_rows) {
  long long idx = (long long)blockIdx.x * 256 + threadIdx.x;
  if (idx >= n_rows * 64) return;          // 64 threads per row, 8 pairs each
  long long row = idx >> 6;
  int j0 = (int)(idx & 63) * 8;
  u16* p = U + row * D_MODEL + j0;
  bf16x8 re8 = *(const bf16x8*)p;
  bf16x8 im8 = *(const bf16x8*)(p + N_HALF);
  bf16x8 ro, io;
#pragma unroll
  for (int i = 0; i < 8; i++) {
    float re = bf2f((u16)re8[i]);
    float im = bf2f((u16)im8[i]);
    float n2 = re * re + im * im;
    float cr = 1.f, sr = 0.f;
    if (n2 > 0.f) {
      float inv = 1.0f / sqrtf(n2);
      cr = re * inv; sr = im * inv;
    }
    ro[i] = (short)f2bf(cr);
    io[i] = (short)f2bf(sr);
  }
  *(bf16x8*)p = ro;
  *(bf16x8*)(p + N_HALF) = io;
}

// ============================================================
// Row softmax: fp32 in (chaotic), bf16 out (attn). 1 block / row.
// ============================================================
__global__ __launch_bounds__(256)
void softmax_bf(const float* __restrict__ Cc, u16* __restrict__ P) {
  const long long row = (long long)blockIdx.y * S_LEN + blockIdx.x;
  const float* p = Cc + row * S_LEN;
  u16* q = P + row * S_LEN;
  const int tid = threadIdx.x;
  float v[8];
  float m = -3.402823466e+38f;
#pragma unroll
  for (int i = 0; i < 8; i++) { v[i] = p[tid + i * 256]; m = fmaxf(m, v[i]); }
#pragma unroll
  for (int mask = 1; mask < 64; mask <<= 1) m = fmaxf(m, __shfl_xor(m, mask));
  __shared__ float red[8];
  if ((tid & 63) == 0) red[tid >> 6] = m;
  __syncthreads();
  m = fmaxf(fmaxf(red[0], red[1]), fmaxf(red[2], red[3]));
  float s = 0.f;
#pragma unroll
  for (int i = 0; i < 8; i++) { v[i] = __expf(v[i] - m); s += v[i]; }
#pragma unroll
  for (int mask = 1; mask < 64; mask <<= 1) s += __shfl_xor(s, mask);
  __syncthreads();
  if ((tid & 63) == 0) red[4 + (tid >> 6)] = s;
  __syncthreads();
  s = red[4] + red[5] + red[6] + red[7];
  float inv = 1.0f / s;
#pragma unroll
  for (int i = 0; i < 8; i++) q[tid + i * 256] = f2bf(v[i] * inv);
}

// ============================================================
// sync_loss
// ============================================================
__global__ __launch_bounds__(1024)
void syncloss_kernel(const float* __restrict__ ssum, const float* __restrict__ ssq,
                     float* __restrict__ out) {
  const int tid = threadIdx.x;
  float acc = 0.f;
  for (int r = tid; r < N_BATCH * S_LEN; r += 1024) {
    float su = ssum[r], sq = ssq[r];
    acc += (sq - su * su * (1.0f / 2048.0f)) * (1.0f / 2047.0f);
  }
#pragma unroll
  for (int mask = 1; mask < 64; mask <<= 1) acc += __shfl_xor(acc, mask);
  __shared__ float red[16];
  if ((tid & 63) == 0) red[tid >> 6] = acc;
  __syncthreads();
  if (tid == 0) {
    float t = 0.f;
#pragma unroll
    for (int k = 0; k < 16; k++) t += red[k];
    out[0] = 0.01f * (t / (float)(N_BATCH * S_LEN));
  }
}

extern "C" void kernel_launch(void* const* d_in, const int* in_sizes, int n_in,
                              void* d_out, int out_size, void* d_ws, size_t ws_size,
                              hipStream_t stream) {
  const float* x    = (const float*)d_in[0];
  const float* Wq   = (const float*)d_in[1];
  const float* bq   = (const float*)d_in[2];
  const float* Wk   = (const float*)d_in[3];
  const float* bk   = (const float*)d_in[4];
  const float* Wv   = (const float*)d_in[5];
  const float* bv   = (const float*)d_in[6];
  const float* Wp   = (const float*)d_in[7];
  const float* bp   = (const float*)d_in[8];
  const float* Wo   = (const float*)d_in[9];
  const float* bo   = (const float*)d_in[10];
  const float* bifp = (const float*)d_in[11];
  const float* pcp  = (const float*)d_in[12];
  float* out = (float*)d_out;

  const long long NROW = (long long)N_BATCH * S_LEN;   // 8192
  const long long TD   = NROW * D_MODEL;               // 8,388,608
  const long long WSZ  = (long long)D_MODEL * D_MODEL; // 1,048,576

  // workspace layout (~171 MB)
  u16* xbf   = (u16*)d_ws;          // TD
  u16* wqb   = xbf + TD;            // WSZ
  u16* wkb   = wqb + WSZ;           // WSZ
  u16* wpb   = wkb + WSZ;           // WSZ
  u16* woh   = wpb + WSZ;           // WSZ (Wo hi/lo)
  u16* wol   = woh + WSZ;
  u16* wvth  = wol + WSZ;           // WSZ (Wv^T hi/lo)
  u16* wvtl  = wvth + WSZ;
  u16* w2h   = wvtl + WSZ;          // WSZ (W2 hi/lo)
  u16* w2l   = w2h + WSZ;
  float* W2f = (float*)(w2l + WSZ); // WSZ floats (4 MB)
  float* w2b = W2f + WSZ;           // 1024 floats
  u16* Qbf   = (u16*)(w2b + D_MODEL); // TD
  u16* Kbf   = Qbf + TD;            // TD (contiguous)
  u16* pfQ   = Kbf + TD;            // TD
  u16* pfK   = pfQ + TD;            // TD (contiguous)
  float* Cc  = (float*)(pfK + TD);  // B*S*S fp32 (67 MB)
  float* ssum = Cc + (long long)N_BATCH * S_LEN * S_LEN;
  float* ssq  = ssum + NROW;
  u16* attn = Qbf;                  // overlays Q+K after chaotic (2*TD)
  u16* vwh  = pfQ;                  // overlays Uq after chaotic
  u16* vwl  = pfK;                  // overlays Uk after chaotic

  dim3 blk(256);
  const long long sQ = (long long)S_LEN * D_MODEL;   // 2048*1024
  const long long sS = (long long)S_LEN * S_LEN;

  // ---- casts & W2 precompute ----
  cast_bf4<<<(int)(TD / 4 / 256), blk, 0, stream>>>(x, xbf, TD / 4);
  cast_bf4<<<(int)(WSZ / 4 / 256), blk, 0, stream>>>(Wq, wqb, WSZ / 4);
  cast_bf4<<<(int)(WSZ / 4 / 256), blk, 0, stream>>>(Wk, wkb, WSZ / 4);
  cast_bf4<<<(int)(WSZ / 4 / 256), blk, 0, stream>>>(Wp, wpb, WSZ / 4);
  cast_split<<<(int)(WSZ / 256), blk, 0, stream>>>(Wo, woh, wol, WSZ);
  transpose_split<<<dim3(32, 32), blk, 0, stream>>>(Wv, wvth, wvtl);
  // W2 = split(Wo) @ split(Wv^T)^T  (fp32), then split; w2b = Wo @ bv
  mfma_gemm_out3<<<dim3(8, 8, 1), blk, 0, stream>>>(
      woh, wol, wvth, wvtl, nullptr, W2f, D_MODEL, D_MODEL);
  cast_split<<<(int)(WSZ / 256), blk, 0, stream>>>(W2f, w2h, w2l, WSZ);
  w2_bias<<<D_MODEL, blk, 0, stream>>>(Wo, bv, w2b);

  // ---- Q,K fused projection ----
  qk_fused<<<dim3(8, 64), blk, 0, stream>>>(xbf, wqb, wkb, bq, bk, Qbf, Kbf);
  // ---- pfQ,pfK fused projection ----
  pf_fused<<<dim3(8, 64), blk, 0, stream>>>(Qbf, wpb, bp, pfQ, pfK, TD);
  phase_norm_bf<<<(int)(2 * NROW * 64 / 256), blk, 0, stream>>>(pfQ, 2 * NROW);
  zero_stats<<<(int)((2 * NROW + 255) / 256), blk, 0, stream>>>(ssum, (int)(2 * NROW));

  // ---- fused scores + sync + chaotic ----
  chaotic_fused<<<dim3(16, 16, N_BATCH), blk, 0, stream>>>(
      Qbf, Kbf, pfQ, pfK, Cc, ssum, ssq, bifp, pcp);
  // ---- VWt = split(W2) @ x_b^T + w2b (overlays pf, dead after chaotic) ----
  vwt_kernel<<<dim3(16, 8, N_BATCH), blk, 0, stream>>>(
      w2h, w2l, xbf, w2b, vwh, vwl, sQ, sQ);
  // ---- softmax (overlays Q/K) ----
  softmax_bf<<<dim3(S_LEN, N_BATCH), blk, 0, stream>>>(Cc, attn);
  // ---- out = attn @ (VWth+VWtl)^T + bo ----
  gemm_bsplit<<<dim3(8, 16, N_BATCH), blk, 0, stream>>>(
      attn, vwh, vwl, bo, out,
      D_MODEL, S_LEN, sS, sQ, sQ);
  // ---- sync_loss ----
  syncloss_kernel<<<1, 1024, 0, stream>>>(ssum, ssq, out + TD);
}

// Round 4
// 487.430 us; speedup vs baseline: 1.1589x; 1.0018x over previous
//
#include <hip/hip_runtime.h>
#include <hip/hip_bf16.h>
#include <math.h>

#define S_LEN 2048
#define D_MODEL 1024
#define N_BATCH 4
#define N_HALF 512

typedef unsigned short u16;
typedef __attribute__((ext_vector_type(8))) short bf16x8;
typedef __attribute__((ext_vector_type(4))) float f32x4;

// ---------- helpers ----------
__device__ inline u16 f2bf(float v) {
  __hip_bfloat16 h = __float2bfloat16(v);   // RNE
  return *reinterpret_cast<u16*>(&h);
}
__device__ inline float bf2f(u16 u) {
  __hip_bfloat16 h = *reinterpret_cast<__hip_bfloat16*>(&u);
  return __bfloat162float(h);
}
// async global->LDS, 16B per lane; LDS dest is wave-uniform base + lane*16
__device__ inline void gl2lds16(const void* g, void* l) {
  __builtin_amdgcn_global_load_lds(
      (const __attribute__((address_space(1))) unsigned int*)g,
      (__attribute__((address_space(3))) unsigned int*)l, 16, 0, 0);
}
// tanh via v_exp_f32; exact at 0, saturates correctly at +/-inf (no NaN)
__device__ inline float fast_tanh(float x) {
  float e = __expf(2.0f * x);
  return 1.0f - 2.0f / (e + 1.0f);
}

// ---------- casts ----------
// one launch for x, Wq, Wk, Wp (float4 granularity; sizes are pow2)
#define N0_X   (2097152LL)   // TD/4
#define NW_W   (262144LL)    // WSZ/4
__global__ __launch_bounds__(256)
void cast_bf4_multi(const float* __restrict__ sx, u16* __restrict__ dx,
                    const float* __restrict__ s1, u16* __restrict__ d1,
                    const float* __restrict__ s2, u16* __restrict__ d2,
                    const float* __restrict__ s3, u16* __restrict__ d3) {
  long long i = (long long)blockIdx.x * 256 + threadIdx.x;
  const float* s; u16* d; long long off;
  if (i < N0_X) { s = sx; d = dx; off = i; }
  else {
    long long k = i - N0_X;
    int w = (int)(k >> 18);              // k / NW_W
    off = k & (NW_W - 1);
    s = (w == 0) ? s1 : (w == 1) ? s2 : s3;
    d = (w == 0) ? d1 : (w == 1) ? d2 : d3;
  }
  float4 v = ((const float4*)s)[off];
  ushort4 o;
  o.x = f2bf(v.x); o.y = f2bf(v.y); o.z = f2bf(v.z); o.w = f2bf(v.w);
  ((ushort4*)d)[off] = o;
}
__global__ __launch_bounds__(256)
void cast_split(const float* __restrict__ src, u16* __restrict__ hi,
                u16* __restrict__ lo, long long n) {
  long long i = (long long)blockIdx.x * 256 + threadIdx.x;
  if (i < n) {
    float v = src[i];
    u16 h = f2bf(v);
    hi[i] = h;
    lo[i] = f2bf(v - bf2f(h));
  }
}
// transpose + split: dst[i][j] = split(src[j][i]), 1024x1024
__global__ __launch_bounds__(256)
void transpose_split(const float* __restrict__ src, u16* __restrict__ hi,
                     u16* __restrict__ lo) {
  __shared__ float t[32][33];
  const int bx = blockIdx.x * 32;   // i-base (src col, dst row)
  const int by = blockIdx.y * 32;   // j-base (src row, dst col)
  const int c = threadIdx.x & 31;
  const int r0 = (threadIdx.x >> 5) * 4;
#pragma unroll
  for (int r = 0; r < 4; r++)
    t[r0 + r][c] = src[(long long)(by + r0 + r) * D_MODEL + bx + c];
  __syncthreads();
#pragma unroll
  for (int r = 0; r < 4; r++) {
    float v = t[c][r0 + r];
    long long idx = (long long)(bx + r0 + r) * D_MODEL + by + c;
    u16 h = f2bf(v);
    hi[idx] = h;
    lo[idx] = f2bf(v - bf2f(h));
  }
}
// w2b[d] = sum_j Wo[d][j] * bv[j]   (one block per d)
__global__ __launch_bounds__(256)
void w2_bias(const float* __restrict__ Wo, const float* __restrict__ bv,
             float* __restrict__ w2b) {
  const int d = blockIdx.x;
  const int tid = threadIdx.x;
  float acc = 0.f;
  for (int j = tid; j < D_MODEL; j += 256)
    acc += Wo[(long long)d * D_MODEL + j] * bv[j];
#pragma unroll
  for (int m = 1; m < 64; m <<= 1) acc += __shfl_xor(acc, m);
  __shared__ float red[4];
  if ((tid & 63) == 0) red[tid >> 6] = acc;
  __syncthreads();
  if (tid == 0) w2b[d] = red[0] + red[1] + red[2] + red[3];
}

// ============================================================
// Staging/read geometry shared by all BK=64 swizzled GEMMs
// (validated round 2/3: SQ_LDS_BANK_CONFLICT -> 0):
//   one gl2lds = 1KB = 8 rows x 64 u16; lane l -> LDS row l>>3, c16blk l&7.
//   global source col16 pre-swizzled: c16blk_src = (l&7) ^ (l>>3).
//   read of k-block kblk at row rr comes from LDS col block kblk ^ (rr&7).
// ============================================================

// ============================================================
// Fused Q+K projection: dual-acc NT GEMM sharing the A (=x) staging.
// BK=64 + XOR swizzle, 48 KB LDS, 2 blocks/CU.
// ============================================================
__global__ __launch_bounds__(256, 2)
void qk_fused(const u16* __restrict__ X, const u16* __restrict__ Wq,
              const u16* __restrict__ Wk,
              const float* __restrict__ bq, const float* __restrict__ bk,
              u16* __restrict__ Qo, u16* __restrict__ Ko) {
  __shared__ u16 Xs[128 * 64];
  __shared__ u16 Qs[128 * 64];
  __shared__ u16 Ks[128 * 64];
  const int tid  = threadIdx.x;
  const int wave = tid >> 6;
  const int lane = tid & 63;
  const int quad = lane >> 4;
  const int tc   = lane & 15;
  const int bm = blockIdx.y * 128;
  const int bn = blockIdx.x * 128;
  const int wm = (wave & 1) * 64;
  const int wn = (wave >> 1) * 64;

  f32x4 acc1[4][4], acc2[4][4];
#pragma unroll
  for (int i = 0; i < 4; i++)
#pragma unroll
    for (int j = 0; j < 4; j++) {
      acc1[i][j] = (f32x4){0.f, 0.f, 0.f, 0.f};
      acc2[i][j] = (f32x4){0.f, 0.f, 0.f, 0.f};
    }

  const int srow8 = lane >> 3;
  const int scol  = ((lane & 7) ^ srow8) * 8;
  const int srowb = wave * 32;
  const u16* gx = X  + (long long)(bm + srowb + srow8) * D_MODEL + scol;
  const u16* gq = Wq + (long long)(bn + srowb + srow8) * D_MODEL + scol;
  const u16* gk = Wk + (long long)(bn + srowb + srow8) * D_MODEL + scol;
  const int wb = srowb * 64;
  const long long r8 = 8LL * D_MODEL;
  const int swzA = tc & 7;

  for (int k0 = 0; k0 < D_MODEL; k0 += 64) {
#pragma unroll
    for (int c = 0; c < 4; c++) {
      gl2lds16(gx + c * r8, Xs + wb + c * 512);
      gl2lds16(gq + c * r8, Qs + wb + c * 512);
      gl2lds16(gk + c * r8, Ks + wb + c * 512);
    }
    gx += 64; gq += 64; gk += 64;
    __syncthreads();
    bf16x8 af[4][2], bq4[4][2], bk4[4][2];
#pragma unroll
    for (int i = 0; i < 4; i++) {
      const int ra = (wm + i * 16 + tc) * 64;
      const int rb = (wn + i * 16 + tc) * 64;
#pragma unroll
      for (int ks = 0; ks < 2; ks++) {
        const int co = ((ks * 4 + quad) ^ swzA) * 8;
        af[i][ks]  = *(const bf16x8*)(Xs + ra + co);
        bq4[i][ks] = *(const bf16x8*)(Qs + rb + co);
        bk4[i][ks] = *(const bf16x8*)(Ks + rb + co);
      }
    }
#pragma unroll
    for (int i = 0; i < 4; i++)
#pragma unroll
      for (int j = 0; j < 4; j++) {
        acc1[i][j] = __builtin_amdgcn_mfma_f32_16x16x32_bf16(af[i][0], bq4[j][0], acc1[i][j], 0, 0, 0);
        acc2[i][j] = __builtin_amdgcn_mfma_f32_16x16x32_bf16(af[i][0], bk4[j][0], acc2[i][j], 0, 0, 0);
        acc1[i][j] = __builtin_amdgcn_mfma_f32_16x16x32_bf16(af[i][1], bq4[j][1], acc1[i][j], 0, 0, 0);
        acc2[i][j] = __builtin_amdgcn_mfma_f32_16x16x32_bf16(af[i][1], bk4[j][1], acc2[i][j], 0, 0, 0);
      }
    __syncthreads();
  }

#pragma unroll
  for (int i = 0; i < 4; i++) {
    const int row0 = bm + wm + i * 16 + quad * 4;
#pragma unroll
    for (int j = 0; j < 4; j++) {
      const int col = bn + wn + j * 16 + tc;
#pragma unroll
      for (int r = 0; r < 4; r++) {
        long long idx = (long long)(row0 + r) * D_MODEL + col;
        Qo[idx] = f2bf(acc1[i][j][r] + bq[col]);
        Ko[idx] = f2bf(acc2[i][j][r] + bk[col]);
      }
    }
  }
}

// ============================================================
// Fused pfQ+pfK projection + IN-KERNEL PHASE NORMALIZE.
//   B-tile covers Wp rows [bn,bn+64) (re) U [bn+512,bn+576) (im), bn=bx*64.
//   Waves wn=0 hold re-cols, wn=64 hold im-cols of the SAME (row, c) pairs;
//   partner wave = wave^2. After the K-loop the staging LDS is reused as an
//   fp32 exchange buffer (4 rounds, b128 lane-linear = conflict-free), then
//   each wave writes its normalized half directly (re/sqrt, im/sqrt).
//   Removes the separate phase_norm kernel (134 MB HBM round-trip).
// ============================================================
__global__ __launch_bounds__(256, 2)
void pf_fused(const u16* __restrict__ Qb, const u16* __restrict__ Wp,
              const float* __restrict__ bp,
              u16* __restrict__ pfQ, u16* __restrict__ pfK,
              long long TDo) {
  __shared__ u16 lds_all[3 * 128 * 64];   // Qs | Ks | Ws (48 KB)
  u16* Qs = lds_all;
  u16* Ks = lds_all + 128 * 64;
  u16* Ws = lds_all + 2 * 128 * 64;
  const int tid  = threadIdx.x;
  const int wave = tid >> 6;
  const int lane = tid & 63;
  const int quad = lane >> 4;
  const int tc   = lane & 15;
  const int bm = blockIdx.y * 128;
  const int bn = blockIdx.x * 64;          // re-col base (im = +512)
  const int wm = (wave & 1) * 64;
  const int grp = wave >> 1;               // 0: re-group, 1: im-group

  f32x4 acc1[4][4], acc2[4][4];
#pragma unroll
  for (int i = 0; i < 4; i++)
#pragma unroll
    for (int j = 0; j < 4; j++) {
      acc1[i][j] = (f32x4){0.f, 0.f, 0.f, 0.f};
      acc2[i][j] = (f32x4){0.f, 0.f, 0.f, 0.f};
    }

  const int srow8 = lane >> 3;
  const int scol  = ((lane & 7) ^ srow8) * 8;
  const int srowb = wave * 32;
  const u16* gq = Qb + (long long)(bm + srowb + srow8) * D_MODEL + scol;
  const u16* gk = gq + TDo;
  // B-tile row t -> Wp row: t<64 ? bn+t : 512+bn+(t-64)  (waves 2,3 are t>=64)
  const u16* gw = Wp + (long long)(bn + srowb + srow8 + ((wave & 2) ? 448 : 0)) * D_MODEL + scol;
  const int wb = srowb * 64;
  const long long r8 = 8LL * D_MODEL;
  const int swzA = tc & 7;

  for (int k0 = 0; k0 < D_MODEL; k0 += 64) {
#pragma unroll
    for (int c = 0; c < 4; c++) {
      gl2lds16(gq + c * r8, Qs + wb + c * 512);
      gl2lds16(gk + c * r8, Ks + wb + c * 512);
      gl2lds16(gw + c * r8, Ws + wb + c * 512);
    }
    gq += 64; gk += 64; gw += 64;
    __syncthreads();
    bf16x8 aq[4][2], ak[4][2], bw[4][2];
    const int wn = grp * 64;
#pragma unroll
    for (int i = 0; i < 4; i++) {
      const int ra = (wm + i * 16 + tc) * 64;
      const int rb = (wn + i * 16 + tc) * 64;
#pragma unroll
      for (int ks = 0; ks < 2; ks++) {
        const int co = ((ks * 4 + quad) ^ swzA) * 8;
        aq[i][ks] = *(const bf16x8*)(Qs + ra + co);
        ak[i][ks] = *(const bf16x8*)(Ks + ra + co);
        bw[i][ks] = *(const bf16x8*)(Ws + rb + co);
      }
    }
#pragma unroll
    for (int i = 0; i < 4; i++)
#pragma unroll
      for (int j = 0; j < 4; j++) {
        acc1[i][j] = __builtin_amdgcn_mfma_f32_16x16x32_bf16(aq[i][0], bw[j][0], acc1[i][j], 0, 0, 0);
        acc2[i][j] = __builtin_amdgcn_mfma_f32_16x16x32_bf16(ak[i][0], bw[j][0], acc2[i][j], 0, 0, 0);
        acc1[i][j] = __builtin_amdgcn_mfma_f32_16x16x32_bf16(aq[i][1], bw[j][1], acc1[i][j], 0, 0, 0);
        acc2[i][j] = __builtin_amdgcn_mfma_f32_16x16x32_bf16(ak[i][1], bw[j][1], acc2[i][j], 0, 0, 0);
      }
    __syncthreads();
  }

  // ---- fused phase-normalize epilogue (exchange via LDS, 4 rounds) ----
  float* ex = (float*)lds_all;             // 32 KB of the 48 KB staging
  const long long colbase = (long long)bn + (long long)grp * 512;
#pragma unroll
  for (int o = 0; o < 2; o++) {
    u16* Ou = o ? pfK : pfQ;
#pragma unroll
    for (int half = 0; half < 2; half++) {
      int cnt = 0;
#pragma unroll
      for (int i = 2 * half; i < 2 * half + 2; i++)
#pragma unroll
        for (int j = 0; j < 4; j++) {
          f32x4 v = o ? acc2[i][j] : acc1[i][j];
          float b = bp[colbase + j * 16 + tc];
          v[0] += b; v[1] += b; v[2] += b; v[3] += b;
          *(f32x4*)(ex + wave * 2048 + cnt * 256 + lane * 4) = v;
          cnt++;
        }
      __syncthreads();
      cnt = 0;
#pragma unroll
      for (int i = 2 * half; i < 2 * half + 2; i++)
#pragma unroll
        for (int j = 0; j < 4; j++) {
          f32x4 own = *(const f32x4*)(ex + wave * 2048 + cnt * 256 + lane * 4);
          f32x4 oth = *(const f32x4*)(ex + (wave ^ 2) * 2048 + cnt * 256 + lane * 4);
          const int row0 = bm + wm + i * 16 + quad * 4;
          const long long col = colbase + j * 16 + tc;
#pragma unroll
          for (int r = 0; r < 4; r++) {
            float a = own[r], p = oth[r];
            float n2 = a * a + p * p;
            float outv = (grp == 0) ? 1.f : 0.f;
            if (n2 > 0.f) outv = a * (1.0f / sqrtf(n2));
            Ou[(long long)(row0 + r) * D_MODEL + col] = f2bf(outv);
          }
          cnt++;
        }
      __syncthreads();
    }
  }
}

// ============================================================
// Split-precision GEMM: C = (Ah+Al)(Bh+Bl)^T (+bias), fp32 out.
// 3 MFMAs per frag step. BK=64 + XOR swizzle, 64 KB LDS.
// ============================================================
__global__ __launch_bounds__(256)
void mfma_gemm_out3(const u16* __restrict__ Ah, const u16* __restrict__ Al,
                    const u16* __restrict__ Bh, const u16* __restrict__ Bl,
                    const float* __restrict__ bias, float* __restrict__ C,
                    int N, int K) {
  __shared__ u16 Ash[128 * 64];
  __shared__ u16 Asl[128 * 64];
  __shared__ u16 Bsh[128 * 64];
  __shared__ u16 Bsl[128 * 64];
  const int tid  = threadIdx.x;
  const int wave = tid >> 6;
  const int lane = tid & 63;
  const int quad = lane >> 4;
  const int tc   = lane & 15;
  const int bm = blockIdx.y * 128;
  const int bn = blockIdx.x * 128;
  const int wm = (wave & 1) * 64;
  const int wn = (wave >> 1) * 64;

  f32x4 acc[4][4];
#pragma unroll
  for (int i = 0; i < 4; i++)
#pragma unroll
    for (int j = 0; j < 4; j++) acc[i][j] = (f32x4){0.f, 0.f, 0.f, 0.f};

  const int srow8 = lane >> 3;
  const int scol  = ((lane & 7) ^ srow8) * 8;
  const int srowb = wave * 32;
  long long aoff = (long long)(bm + srowb + srow8) * K + scol;
  long long boff = (long long)(bn + srowb + srow8) * K + scol;
  const u16 *gah = Ah + aoff, *gal = Al + aoff;
  const u16 *gbh = Bh + boff, *gbl = Bl + boff;
  const int wb = srowb * 64;
  const long long r8K = 8LL * K;
  const int swzA = tc & 7;

  for (int k0 = 0; k0 < K; k0 += 64) {
#pragma unroll
    for (int c = 0; c < 4; c++) {
      gl2lds16(gah + c * r8K, Ash + wb + c * 512);
      gl2lds16(gal + c * r8K, Asl + wb + c * 512);
      gl2lds16(gbh + c * r8K, Bsh + wb + c * 512);
      gl2lds16(gbl + c * r8K, Bsl + wb + c * 512);
    }
    gah += 64; gal += 64; gbh += 64; gbl += 64;
    __syncthreads();
    bf16x8 ah[4][2], al[4][2], bh[4][2], bl[4][2];
#pragma unroll
    for (int i = 0; i < 4; i++) {
      const int ra = (wm + i * 16 + tc) * 64;
      const int rb = (wn + i * 16 + tc) * 64;
#pragma unroll
      for (int ks = 0; ks < 2; ks++) {
        const int co = ((ks * 4 + quad) ^ swzA) * 8;
        ah[i][ks] = *(const bf16x8*)(Ash + ra + co);
        al[i][ks] = *(const bf16x8*)(Asl + ra + co);
        bh[i][ks] = *(const bf16x8*)(Bsh + rb + co);
        bl[i][ks] = *(const bf16x8*)(Bsl + rb + co);
      }
    }
#pragma unroll
    for (int i = 0; i < 4; i++)
#pragma unroll
      for (int j = 0; j < 4; j++) {
#pragma unroll
        for (int ks = 0; ks < 2; ks++) {
          acc[i][j] = __builtin_amdgcn_mfma_f32_16x16x32_bf16(ah[i][ks], bh[j][ks], acc[i][j], 0, 0, 0);
          acc[i][j] = __builtin_amdgcn_mfma_f32_16x16x32_bf16(ah[i][ks], bl[j][ks], acc[i][j], 0, 0, 0);
          acc[i][j] = __builtin_amdgcn_mfma_f32_16x16x32_bf16(al[i][ks], bh[j][ks], acc[i][j], 0, 0, 0);
        }
      }
    __syncthreads();
  }
#pragma unroll
  for (int i = 0; i < 4; i++) {
    const int row0 = bm + wm + i * 16 + quad * 4;
#pragma unroll
    for (int j = 0; j < 4; j++) {
      const int col = bn + wn + j * 16 + tc;
      float b = bias ? bias[col] : 0.f;
#pragma unroll
      for (int r = 0; r < 4; r++)
        C[(long long)(row0 + r) * N + col] = acc[i][j][r] + b;
    }
  }
}

// ============================================================
// VWt[b][d][s] = (W2h+W2l) @ x_b^T + w2b[d], hi/lo bf16 out.
// BK=64 + XOR swizzle, 48 KB LDS.
// ============================================================
__global__ __launch_bounds__(256)
void vwt_kernel(const u16* __restrict__ W2h, const u16* __restrict__ W2l,
                const u16* __restrict__ X, const float* __restrict__ w2b,
                u16* __restrict__ Ch, u16* __restrict__ Cl,
                long long sB, long long sC) {
  __shared__ u16 Ah[128 * 64];
  __shared__ u16 Al[128 * 64];
  __shared__ u16 Bs[128 * 64];
  const int tid  = threadIdx.x;
  const int wave = tid >> 6;
  const int lane = tid & 63;
  const int quad = lane >> 4;
  const int tc   = lane & 15;
  const int bm = blockIdx.y * 128;   // d
  const int bn = blockIdx.x * 128;   // s
  const long long z = blockIdx.z;
  const int wm = (wave & 1) * 64;
  const int wn = (wave >> 1) * 64;

  f32x4 acc[4][4];
#pragma unroll
  for (int i = 0; i < 4; i++)
#pragma unroll
    for (int j = 0; j < 4; j++) acc[i][j] = (f32x4){0.f, 0.f, 0.f, 0.f};

  const int srow8 = lane >> 3;
  const int scol  = ((lane & 7) ^ srow8) * 8;
  const int srowb = wave * 32;
  const long long aoff = (long long)(bm + srowb + srow8) * D_MODEL + scol;
  const u16* gah = W2h + aoff;
  const u16* gal = W2l + aoff;
  const u16* gb  = X + z * sB + (long long)(bn + srowb + srow8) * D_MODEL + scol;
  const int wb = srowb * 64;
  const long long r8 = 8LL * D_MODEL;
  const int swzA = tc & 7;

  for (int k0 = 0; k0 < D_MODEL; k0 += 64) {
#pragma unroll
    for (int c = 0; c < 4; c++) {
      gl2lds16(gah + c * r8, Ah + wb + c * 512);
      gl2lds16(gal + c * r8, Al + wb + c * 512);
      gl2lds16(gb  + c * r8, Bs + wb + c * 512);
    }
    gah += 64; gal += 64; gb += 64;
    __syncthreads();
    bf16x8 ah4[4][2], al4[4][2], bx[4][2];
#pragma unroll
    for (int i = 0; i < 4; i++) {
      const int ra = (wm + i * 16 + tc) * 64;
      const int rb = (wn + i * 16 + tc) * 64;
#pragma unroll
      for (int ks = 0; ks < 2; ks++) {
        const int co = ((ks * 4 + quad) ^ swzA) * 8;
        ah4[i][ks] = *(const bf16x8*)(Ah + ra + co);
        al4[i][ks] = *(const bf16x8*)(Al + ra + co);
        bx[i][ks]  = *(const bf16x8*)(Bs + rb + co);
      }
    }
#pragma unroll
    for (int i = 0; i < 4; i++)
#pragma unroll
      for (int j = 0; j < 4; j++) {
        acc[i][j] = __builtin_amdgcn_mfma_f32_16x16x32_bf16(ah4[i][0], bx[j][0], acc[i][j], 0, 0, 0);
        acc[i][j] = __builtin_amdgcn_mfma_f32_16x16x32_bf16(al4[i][0], bx[j][0], acc[i][j], 0, 0, 0);
        acc[i][j] = __builtin_amdgcn_mfma_f32_16x16x32_bf16(ah4[i][1], bx[j][1], acc[i][j], 0, 0, 0);
        acc[i][j] = __builtin_amdgcn_mfma_f32_16x16x32_bf16(al4[i][1], bx[j][1], acc[i][j], 0, 0, 0);
      }
    __syncthreads();
  }

  u16* Chz = Ch + z * sC;
  u16* Clz = Cl + z * sC;
#pragma unroll
  for (int i = 0; i < 4; i++) {
    const int row0 = bm + wm + i * 16 + quad * 4;
#pragma unroll
    for (int j = 0; j < 4; j++) {
      const int col = bn + wn + j * 16 + tc;
#pragma unroll
      for (int r = 0; r < 4; r++) {
        float v = acc[i][j][r] + w2b[row0 + r];
        long long idx = (long long)(row0 + r) * S_LEN + col;
        u16 h = f2bf(v);
        Chz[idx] = h;
        Clz[idx] = f2bf(v - bf2f(h));
      }
    }
  }
}

// ============================================================
// B-split GEMM (out): C = A @ (Bh+Bl)^T + bias[col], fp32 out.
// BK=64 + XOR swizzle, 48 KB LDS.
// ============================================================
__global__ __launch_bounds__(256)
void gemm_bsplit(const u16* __restrict__ A,
                 const u16* __restrict__ Bh, const u16* __restrict__ Bl,
                 const float* __restrict__ bias, float* __restrict__ C,
                 int N, int K, long long sA, long long sB, long long sC) {
  __shared__ u16 As[128 * 64];
  __shared__ u16 Bsh[128 * 64];
  __shared__ u16 Bsl[128 * 64];
  const int tid  = threadIdx.x;
  const int wave = tid >> 6;
  const int lane = tid & 63;
  const int quad = lane >> 4;
  const int tc   = lane & 15;
  const int bm = blockIdx.y * 128;
  const int bn = blockIdx.x * 128;
  const long long z = blockIdx.z;
  const int wm = (wave & 1) * 64;
  const int wn = (wave >> 1) * 64;

  f32x4 acc[4][4];
#pragma unroll
  for (int i = 0; i < 4; i++)
#pragma unroll
    for (int j = 0; j < 4; j++) acc[i][j] = (f32x4){0.f, 0.f, 0.f, 0.f};

  const int srow8 = lane >> 3;
  const int scol  = ((lane & 7) ^ srow8) * 8;
  const int srowb = wave * 32;
  const long long boff = (long long)(bn + srowb + srow8) * K + scol;
  const u16* ga  = A + z * sA + (long long)(bm + srowb + srow8) * K + scol;
  const u16* gbh = Bh + z * sB + boff;
  const u16* gbl = Bl + z * sB + boff;
  const int wb = srowb * 64;
  const long long r8K = 8LL * K;
  const int swzA = tc & 7;

  for (int k0 = 0; k0 < K; k0 += 64) {
#pragma unroll
    for (int c = 0; c < 4; c++) {
      gl2lds16(ga  + c * r8K, As  + wb + c * 512);
      gl2lds16(gbh + c * r8K, Bsh + wb + c * 512);
      gl2lds16(gbl + c * r8K, Bsl + wb + c * 512);
    }
    ga += 64; gbh += 64; gbl += 64;
    __syncthreads();
    bf16x8 af[4][2], bh[4][2], bl[4][2];
#pragma unroll
    for (int i = 0; i < 4; i++) {
      const int ra = (wm + i * 16 + tc) * 64;
      const int rb = (wn + i * 16 + tc) * 64;
#pragma unroll
      for (int ks = 0; ks < 2; ks++) {
        const int co = ((ks * 4 + quad) ^ swzA) * 8;
        af[i][ks] = *(const bf16x8*)(As  + ra + co);
        bh[i][ks] = *(const bf16x8*)(Bsh + rb + co);
        bl[i][ks] = *(const bf16x8*)(Bsl + rb + co);
      }
    }
#pragma unroll
    for (int i = 0; i < 4; i++)
#pragma unroll
      for (int j = 0; j < 4; j++) {
        acc[i][j] = __builtin_amdgcn_mfma_f32_16x16x32_bf16(af[i][0], bh[j][0], acc[i][j], 0, 0, 0);
        acc[i][j] = __builtin_amdgcn_mfma_f32_16x16x32_bf16(af[i][0], bl[j][0], acc[i][j], 0, 0, 0);
        acc[i][j] = __builtin_amdgcn_mfma_f32_16x16x32_bf16(af[i][1], bh[j][1], acc[i][j], 0, 0, 0);
        acc[i][j] = __builtin_amdgcn_mfma_f32_16x16x32_bf16(af[i][1], bl[j][1], acc[i][j], 0, 0, 0);
      }
    __syncthreads();
  }

  float* Cz = C + z * sC;
#pragma unroll
  for (int i = 0; i < 4; i++) {
    const int row0 = bm + wm + i * 16 + quad * 4;
#pragma unroll
    for (int j = 0; j < 4; j++) {
      const int col = bn + wn + j * 16 + tc;
#pragma unroll
      for (int r = 0; r < 4; r++)
        Cz[(long long)(row0 + r) * N + col] = acc[i][j][r] + bias[col];
    }
  }
}

// ============================================================
// Fused chaotic kernel — BK=64 + XOR-swizzled LDS (round-2 validated body).
// ============================================================
__global__ __launch_bounds__(256, 2)
void chaotic_fused(const u16* __restrict__ Q, const u16* __restrict__ Kt,
                   const u16* __restrict__ Uq, const u16* __restrict__ Uk,
                   float* __restrict__ Cc,
                   float* __restrict__ ssum, float* __restrict__ ssq,
                   const float* __restrict__ bifp, const float* __restrict__ pcp) {
  __shared__ u16 Qs[128 * 64];
  __shared__ u16 Ks[128 * 64];
  __shared__ u16 Us[128 * 64];
  __shared__ u16 Ws[128 * 64];
  const int tid  = threadIdx.x;
  const int wave = tid >> 6;
  const int lane = tid & 63;
  const int quad = lane >> 4;
  const int tc   = lane & 15;
  const int bm = blockIdx.y * 128;
  const int bn = blockIdx.x * 128;
  const long long z = blockIdx.z;
  const long long sQ = (long long)S_LEN * D_MODEL;
  const int wm = (wave & 1) * 64;
  const int wn = (wave >> 1) * 64;

  f32x4 acc1[4][4], acc2[4][4];
#pragma unroll
  for (int i = 0; i < 4; i++)
#pragma unroll
    for (int j = 0; j < 4; j++) {
      acc1[i][j] = (f32x4){0.f, 0.f, 0.f, 0.f};
      acc2[i][j] = (f32x4){0.f, 0.f, 0.f, 0.f};
    }

  const int srow8  = lane >> 3;                     // 0..7
  const int scol   = ((lane & 7) ^ srow8) * 8;      // swizzled col (u16 units)
  const int srowb  = wave * 32;                     // wave's 32-row stripe
  const u16* gq = Q  + z * sQ + (long long)(bm + srowb + srow8) * D_MODEL + scol;
  const u16* gk = Kt + z * sQ + (long long)(bn + srowb + srow8) * D_MODEL + scol;
  const u16* gu = Uq + z * sQ + (long long)(bm + srowb + srow8) * D_MODEL + scol;
  const u16* gw = Uk + z * sQ + (long long)(bn + srowb + srow8) * D_MODEL + scol;
  const int wb = srowb * 64;                        // u16 offset of wave stripe
  const long long r8 = 8LL * D_MODEL;               // 8 rows

  const int swzA = tc & 7;                          // row&7 for read swizzle

  for (int k0 = 0; k0 < D_MODEL; k0 += 64) {
#pragma unroll
    for (int c = 0; c < 4; c++) {
      gl2lds16(gq + c * r8, Qs + wb + c * 512);
      gl2lds16(gk + c * r8, Ks + wb + c * 512);
      gl2lds16(gu + c * r8, Us + wb + c * 512);
      gl2lds16(gw + c * r8, Ws + wb + c * 512);
    }
    gq += 64; gk += 64; gu += 64; gw += 64;
    __syncthreads();
    {   // GEMM 1: scores = Q @ K^T  (two k-slabs per tile)
      bf16x8 af[4][2], bg[4][2];
#pragma unroll
      for (int i = 0; i < 4; i++) {
        const int ra = (wm + i * 16 + tc) * 64;
        const int rb = (wn + i * 16 + tc) * 64;
#pragma unroll
        for (int ks = 0; ks < 2; ks++) {
          const int co = ((ks * 4 + quad) ^ swzA) * 8;
          af[i][ks] = *(const bf16x8*)(Qs + ra + co);
          bg[i][ks] = *(const bf16x8*)(Ks + rb + co);
        }
      }
#pragma unroll
      for (int i = 0; i < 4; i++)
#pragma unroll
        for (int j = 0; j < 4; j++) {
          acc1[i][j] = __builtin_amdgcn_mfma_f32_16x16x32_bf16(af[i][0], bg[j][0], acc1[i][j], 0, 0, 0);
          acc1[i][j] = __builtin_amdgcn_mfma_f32_16x16x32_bf16(af[i][1], bg[j][1], acc1[i][j], 0, 0, 0);
        }
    }
    {   // GEMM 2: sync = cos/sin phase product (Uq @ Uk^T)
      bf16x8 cf[4][2], dg[4][2];
#pragma unroll
      for (int i = 0; i < 4; i++) {
        const int ra = (wm + i * 16 + tc) * 64;
        const int rb = (wn + i * 16 + tc) * 64;
#pragma unroll
        for (int ks = 0; ks < 2; ks++) {
          const int co = ((ks * 4 + quad) ^ swzA) * 8;
          cf[i][ks] = *(const bf16x8*)(Us + ra + co);
          dg[i][ks] = *(const bf16x8*)(Ws + rb + co);
        }
      }
#pragma unroll
      for (int i = 0; i < 4; i++)
#pragma unroll
        for (int j = 0; j < 4; j++) {
          acc2[i][j] = __builtin_amdgcn_mfma_f32_16x16x32_bf16(cf[i][0], dg[j][0], acc2[i][j], 0, 0, 0);
          acc2[i][j] = __builtin_amdgcn_mfma_f32_16x16x32_bf16(cf[i][1], dg[j][1], acc2[i][j], 0, 0, 0);
        }
    }
    __syncthreads();
  }

  const float bif = *bifp;
  const float pc  = *pcp;
  float rsum[4][4], rsq[4][4];
#pragma unroll
  for (int i = 0; i < 4; i++)
#pragma unroll
    for (int r = 0; r < 4; r++) { rsum[i][r] = 0.f; rsq[i][r] = 0.f; }

  float* C = Cc + z * (long long)S_LEN * S_LEN;
#pragma unroll
  for (int i = 0; i < 4; i++) {
    const int row0 = bm + wm + i * 16 + quad * 4;
#pragma unroll
    for (int j = 0; j < 4; j++) {
      const int col = bn + wn + j * 16 + tc;
#pragma unroll
      for (int r = 0; r < 4; r++) {
        float sc = acc1[i][j][r] * 0.03125f;          // / sqrt(1024)
        float sy = acc2[i][j][r] * (1.0f / 512.0f);   // / HALF
        float t  = fast_tanh(sc);
        C[(long long)(row0 + r) * S_LEN + col] = sc + pc * sy + bif * t * (1.0f - t);
        rsum[i][r] += sy;
        rsq[i][r]  += sy * sy;
      }
    }
  }
#pragma unroll
  for (int m = 1; m < 16; m <<= 1) {
#pragma unroll
    for (int i = 0; i < 4; i++)
#pragma unroll
      for (int r = 0; r < 4; r++) {
        rsum[i][r] += __shfl_xor(rsum[i][r], m);
        rsq[i][r]  += __shfl_xor(rsq[i][r], m);
      }
  }
  if (tc == 0) {
#pragma unroll
    for (int i = 0; i < 4; i++)
#pragma unroll
      for (int r = 0; r < 4; r++) {
        long long rr = z * S_LEN + bm + wm + i * 16 + quad * 4 + r;
        atomicAdd(&ssum[rr], rsum[i][r]);
        atomicAdd(&ssq[rr],  rsq[i][r]);
      }
  }
}

// ============================================================
// Row softmax: fp32 in (chaotic), bf16 out (attn). 1 block / row.
// ============================================================
__global__ __launch_bounds__(256)
void softmax_bf(const float* __restrict__ Cc, u16* __restrict__ P) {
  const long long row = (long long)blockIdx.y * S_LEN + blockIdx.x;
  const float* p = Cc + row * S_LEN;
  u16* q = P + row * S_LEN;
  const int tid = threadIdx.x;
  float v[8];
  float m = -3.402823466e+38f;
#pragma unroll
  for (int i = 0; i < 8; i++) { v[i] = p[tid + i * 256]; m = fmaxf(m, v[i]); }
#pragma unroll
  for (int mask = 1; mask < 64; mask <<= 1) m = fmaxf(m, __shfl_xor(m, mask));
  __shared__ float red[8];
  if ((tid & 63) == 0) red[tid >> 6] = m;
  __syncthreads();
  m = fmaxf(fmaxf(red[0], red[1]), fmaxf(red[2], red[3]));
  float s = 0.f;
#pragma unroll
  for (int i = 0; i < 8; i++) { v[i] = __expf(v[i] - m); s += v[i]; }
#pragma unroll
  for (int mask = 1; mask < 64; mask <<= 1) s += __shfl_xor(s, mask);
  __syncthreads();
  if ((tid & 63) == 0) red[4 + (tid >> 6)] = s;
  __syncthreads();
  s = red[4] + red[5] + red[6] + red[7];
  float inv = 1.0f / s;
#pragma unroll
  for (int i = 0; i < 8; i++) q[tid + i * 256] = f2bf(v[i] * inv);
}

// ============================================================
// sync_loss
// ============================================================
__global__ __launch_bounds__(1024)
void syncloss_kernel(const float* __restrict__ ssum, const float* __restrict__ ssq,
                     float* __restrict__ out) {
  const int tid = threadIdx.x;
  float acc = 0.f;
  for (int r = tid; r < N_BATCH * S_LEN; r += 1024) {
    float su = ssum[r], sq = ssq[r];
    acc += (sq - su * su * (1.0f / 2048.0f)) * (1.0f / 2047.0f);
  }
#pragma unroll
  for (int mask = 1; mask < 64; mask <<= 1) acc += __shfl_xor(acc, mask);
  __shared__ float red[16];
  if ((tid & 63) == 0) red[tid >> 6] = acc;
  __syncthreads();
  if (tid == 0) {
    float t = 0.f;
#pragma unroll
    for (int k = 0; k < 16; k++) t += red[k];
    out[0] = 0.01f * (t / (float)(N_BATCH * S_LEN));
  }
}

extern "C" void kernel_launch(void* const* d_in, const int* in_sizes, int n_in,
                              void* d_out, int out_size, void* d_ws, size_t ws_size,
                              hipStream_t stream) {
  const float* x    = (const float*)d_in[0];
  const float* Wq   = (const float*)d_in[1];
  const float* bq   = (const float*)d_in[2];
  const float* Wk   = (const float*)d_in[3];
  const float* bk   = (const float*)d_in[4];
  const float* Wv   = (const float*)d_in[5];
  const float* bv   = (const float*)d_in[6];
  const float* Wp   = (const float*)d_in[7];
  const float* bp   = (const float*)d_in[8];
  const float* Wo   = (const float*)d_in[9];
  const float* bo   = (const float*)d_in[10];
  const float* bifp = (const float*)d_in[11];
  const float* pcp  = (const float*)d_in[12];
  float* out = (float*)d_out;

  const long long NROW = (long long)N_BATCH * S_LEN;   // 8192
  const long long TD   = NROW * D_MODEL;               // 8,388,608
  const long long WSZ  = (long long)D_MODEL * D_MODEL; // 1,048,576

  // workspace layout (~171 MB)
  u16* xbf   = (u16*)d_ws;          // TD
  u16* wqb   = xbf + TD;            // WSZ
  u16* wkb   = wqb + WSZ;           // WSZ
  u16* wpb   = wkb + WSZ;           // WSZ
  u16* woh   = wpb + WSZ;           // WSZ (Wo hi/lo)
  u16* wol   = woh + WSZ;
  u16* wvth  = wol + WSZ;           // WSZ (Wv^T hi/lo)
  u16* wvtl  = wvth + WSZ;
  u16* w2h   = wvtl + WSZ;          // WSZ (W2 hi/lo)
  u16* w2l   = w2h + WSZ;
  float* W2f = (float*)(w2l + WSZ); // WSZ floats (4 MB)
  float* w2b = W2f + WSZ;           // 1024 floats
  u16* Qbf   = (u16*)(w2b + D_MODEL); // TD
  u16* Kbf   = Qbf + TD;            // TD (contiguous)
  u16* pfQ   = Kbf + TD;            // TD
  u16* pfK   = pfQ + TD;            // TD (contiguous)
  float* Cc  = (float*)(pfK + TD);  // B*S*S fp32 (67 MB)
  float* ssum = Cc + (long long)N_BATCH * S_LEN * S_LEN;
  float* ssq  = ssum + NROW;
  u16* attn = Qbf;                  // overlays Q+K after chaotic (2*TD)
  u16* vwh  = pfQ;                  // overlays Uq after chaotic
  u16* vwl  = pfK;                  // overlays Uk after chaotic

  dim3 blk(256);
  const long long sQ = (long long)S_LEN * D_MODEL;   // 2048*1024
  const long long sS = (long long)S_LEN * S_LEN;

  // ---- casts & W2 precompute ----
  cast_bf4_multi<<<11264, blk, 0, stream>>>(x, xbf, Wq, wqb, Wk, wkb, Wp, wpb);
  cast_split<<<(int)(WSZ / 256), blk, 0, stream>>>(Wo, woh, wol, WSZ);
  transpose_split<<<dim3(32, 32), blk, 0, stream>>>(Wv, wvth, wvtl);
  // W2 = split(Wo) @ split(Wv^T)^T  (fp32), then split; w2b = Wo @ bv
  mfma_gemm_out3<<<dim3(8, 8, 1), blk, 0, stream>>>(
      woh, wol, wvth, wvtl, nullptr, W2f, D_MODEL, D_MODEL);
  cast_split<<<(int)(WSZ / 256), blk, 0, stream>>>(W2f, w2h, w2l, WSZ);
  w2_bias<<<D_MODEL, blk, 0, stream>>>(Wo, bv, w2b);

  // ---- Q,K fused projection ----
  qk_fused<<<dim3(8, 64), blk, 0, stream>>>(xbf, wqb, wkb, bq, bk, Qbf, Kbf);
  // ---- pfQ,pfK fused projection + in-kernel phase normalize ----
  pf_fused<<<dim3(8, 64), blk, 0, stream>>>(Qbf, wpb, bp, pfQ, pfK, TD);
  hipMemsetAsync(ssum, 0, (size_t)(2 * NROW) * sizeof(float), stream);

  // ---- fused scores + sync + chaotic ----
  chaotic_fused<<<dim3(16, 16, N_BATCH), blk, 0, stream>>>(
      Qbf, Kbf, pfQ, pfK, Cc, ssum, ssq, bifp, pcp);
  // ---- VWt = split(W2) @ x_b^T + w2b (overlays pf, dead after chaotic) ----
  vwt_kernel<<<dim3(16, 8, N_BATCH), blk, 0, stream>>>(
      w2h, w2l, xbf, w2b, vwh, vwl, sQ, sQ);
  // ---- softmax (overlays Q/K) ----
  softmax_bf<<<dim3(S_LEN, N_BATCH), blk, 0, stream>>>(Cc, attn);
  // ---- out = attn @ (VWth+VWtl)^T + bo ----
  gemm_bsplit<<<dim3(8, 16, N_BATCH), blk, 0, stream>>>(
      attn, vwh, vwl, bo, out,
      D_MODEL, S_LEN, sS, sQ, sQ);
  // ---- sync_loss ----
  syncloss_kernel<<<1, 1024, 0, stream>>>(ssum, ssq, out + TD);
}